// Round 1
// baseline (823.187 us; speedup 1.0000x reference)
//
#include <hip/hip_runtime.h>
#include <math.h>

#define NN 50000
#define EE 800000
#define ETOT (EE + NN)
#define BB 50

// ---------------- CSR build ----------------
__global__ void count_kernel(const int* __restrict__ ei, int* __restrict__ cnt) {
  int e = blockIdx.x * blockDim.x + threadIdx.x;
  if (e >= ETOT) return;
  int d = (e < EE) ? ei[EE + e] : (e - EE);
  atomicAdd(&cnt[d], 1);
}

__global__ void scan1_kernel(const int* __restrict__ cnt, int* __restrict__ rowp,
                             int* __restrict__ part) {
  __shared__ int s[512];
  int t = threadIdx.x;
  int i = blockIdx.x * 512 + t;
  int v = (i < NN) ? cnt[i] : 0;
  s[t] = v;
  __syncthreads();
  for (int off = 1; off < 512; off <<= 1) {
    int add = (t >= off) ? s[t - off] : 0;
    __syncthreads();
    s[t] += add;
    __syncthreads();
  }
  if (i < NN) rowp[i] = s[t] - v;  // exclusive within block
  if (t == 511) part[blockIdx.x] = s[511];
}

__global__ void scan2_kernel(int* part, int* rowp) {
  int run = 0;
  for (int b = 0; b < 98; ++b) { int v = part[b]; part[b] = run; run += v; }
  rowp[NN] = run;  // == ETOT
}

__global__ void scan3_kernel(int* __restrict__ rowp, const int* __restrict__ part) {
  int i = blockIdx.x * 512 + threadIdx.x;
  if (i < NN) rowp[i] += part[blockIdx.x];
}

__global__ void fill_kernel(const int* __restrict__ ei, const int* __restrict__ rowp,
                            int* __restrict__ cur, int* __restrict__ col) {
  int e = blockIdx.x * blockDim.x + threadIdx.x;
  if (e >= ETOT) return;
  int s, d;
  if (e < EE) { s = ei[e]; d = ei[EE + e]; } else { s = e - EE; d = s; }
  int p = atomicAdd(&cur[d], 1);
  col[rowp[d] + p] = s;
}

// ---------------- GEMM: H = A[n,K] @ W[K,CO] ----------------
__global__ __launch_bounds__(256) void gemm_kernel(
    const float* __restrict__ A, const float* __restrict__ B,
    float* __restrict__ Cout, int n, int K, int CO) {
  __shared__ __align__(16) float AsT[16][68];
  __shared__ __align__(16) float Bs[16][68];
  int tx = threadIdx.x % 16, ty = threadIdx.x / 16;
  int r0 = blockIdx.x * 64, c0 = blockIdx.y * 64;
  float acc[4][4];
#pragma unroll
  for (int i = 0; i < 4; ++i)
#pragma unroll
    for (int j = 0; j < 4; ++j) acc[i][j] = 0.f;

  for (int k0 = 0; k0 < K; k0 += 16) {
    int ka = threadIdx.x % 16, ra0 = threadIdx.x / 16;
    int cb = threadIdx.x % 64, kb0 = threadIdx.x / 64;
#pragma unroll
    for (int p = 0; p < 4; ++p) {
      int r = ra0 + p * 16;
      int gr = r0 + r, gk = k0 + ka;
      float v = 0.f;
      if (gr < n && gk < K) v = A[(size_t)gr * K + gk];
      AsT[ka][r] = v;
      int k = kb0 + p * 4;
      int gk2 = k0 + k, gc = c0 + cb;
      float v2 = 0.f;
      if (gk2 < K && gc < CO) v2 = B[(size_t)gk2 * CO + gc];
      Bs[k][cb] = v2;
    }
    __syncthreads();
#pragma unroll
    for (int kk = 0; kk < 16; ++kk) {
      float4 a4 = *(const float4*)&AsT[kk][ty * 4];
      float4 b4 = *(const float4*)&Bs[kk][tx * 4];
      float a[4] = {a4.x, a4.y, a4.z, a4.w};
      float b[4] = {b4.x, b4.y, b4.z, b4.w};
#pragma unroll
      for (int i = 0; i < 4; ++i)
#pragma unroll
        for (int j = 0; j < 4; ++j) acc[i][j] += a[i] * b[j];
    }
    __syncthreads();
  }
#pragma unroll
  for (int i = 0; i < 4; ++i) {
    int gr = r0 + ty * 4 + i;
    if (gr < n) {
      float4 o = make_float4(acc[i][0], acc[i][1], acc[i][2], acc[i][3]);
      *(float4*)&Cout[(size_t)gr * CO + c0 + tx * 4] = o;
    }
  }
}

// ---------------- per-node attention scores ----------------
template <int H>
__global__ void score_kernel(const float* __restrict__ h, const float* __restrict__ aS,
                             const float* __restrict__ aD, float* __restrict__ as_o,
                             float* __restrict__ ad_o) {
  const int CT = H * 64;
  int wid = threadIdx.x >> 6, lane = threadIdx.x & 63;
  int n = blockIdx.x * (blockDim.x >> 6) + wid;
  if (n >= NN) return;
  float ps[H], pd[H];
#pragma unroll
  for (int j = 0; j < H; ++j) {
    float hv = h[(size_t)n * CT + lane + 64 * j];
    ps[j] = hv * aS[lane + 64 * j];
    pd[j] = hv * aD[lane + 64 * j];
  }
#pragma unroll
  for (int j = 0; j < H; ++j) {
    for (int o = 32; o; o >>= 1) {
      ps[j] += __shfl_xor(ps[j], o, 64);
      pd[j] += __shfl_xor(pd[j], o, 64);
    }
  }
  if (lane == 0) {
#pragma unroll
    for (int j = 0; j < H; ++j) {
      as_o[(size_t)n * H + j] = ps[j];
      ad_o[(size_t)n * H + j] = pd[j];
    }
  }
}

// ---------------- softmax-aggregate (one wave per dst node) ----------------
template <int H>
__global__ void agg_kernel(const float* __restrict__ h, const float* __restrict__ as_i,
                           const float* __restrict__ ad_i, const int* __restrict__ rowp,
                           const int* __restrict__ col, const float* __restrict__ bias,
                           float* __restrict__ xo) {
  const int CT = H * 64;
  int wid = threadIdx.x >> 6, lane = threadIdx.x & 63;
  int d = blockIdx.x * (blockDim.x >> 6) + wid;
  if (d >= NN) return;
  int rp0 = rowp[d];
  int deg = rowp[d + 1] - rp0;
  float add[H];
#pragma unroll
  for (int j = 0; j < H; ++j) add[j] = ad_i[(size_t)d * H + j];
  // pass 1: softmax denominator (scores bounded; shift-free exp is safe)
  float den[H];
#pragma unroll
  for (int j = 0; j < H; ++j) den[j] = 0.f;
  for (int i = lane; i < deg; i += 64) {
    int s = col[rp0 + i];
#pragma unroll
    for (int j = 0; j < H; ++j) {
      float e = as_i[(size_t)s * H + j] + add[j];
      e = (e > 0.f) ? e : 0.2f * e;
      den[j] += expf(e);
    }
  }
#pragma unroll
  for (int j = 0; j < H; ++j)
    for (int o = 32; o; o >>= 1) den[j] += __shfl_xor(den[j], o, 64);
  float inv[H];
#pragma unroll
  for (int j = 0; j < H; ++j) inv[j] = 1.f / den[j];
  // pass 2: weighted message accumulate
  float acc[H];
#pragma unroll
  for (int j = 0; j < H; ++j) acc[j] = 0.f;
  for (int i = 0; i < deg; ++i) {
    int s = col[rp0 + i];
#pragma unroll
    for (int j = 0; j < H; ++j) {
      float e = as_i[(size_t)s * H + j] + add[j];
      e = (e > 0.f) ? e : 0.2f * e;
      float al = expf(e) * inv[j];
      acc[j] += al * h[(size_t)s * CT + lane + 64 * j];
    }
  }
#pragma unroll
  for (int j = 0; j < H; ++j) {
    int ch = lane + 64 * j;
    float v = acc[j] + bias[ch];
    v = (v > 0.f) ? v : expm1f(v);  // elu
    xo[(size_t)d * CT + ch] = v;
  }
}

// ---------------- node-attention MLP ----------------
__global__ void na_kernel(const float* __restrict__ x3, const float* __restrict__ W1,
                          const float* __restrict__ b1, const float* __restrict__ W2,
                          const float* __restrict__ b2, float* __restrict__ na) {
  __shared__ float Ws[64 * 32];
  __shared__ float W2s[32];
  for (int i = threadIdx.x; i < 2048; i += blockDim.x) Ws[i] = W1[i];
  if (threadIdx.x < 32) W2s[threadIdx.x] = W2[threadIdx.x];
  __syncthreads();
  int n = blockIdx.x * blockDim.x + threadIdx.x;
  if (n >= NN) return;
  float hid[32];
#pragma unroll
  for (int j = 0; j < 32; ++j) hid[j] = b1[j];
  for (int k = 0; k < 64; ++k) {
    float xv = x3[(size_t)n * 64 + k];
#pragma unroll
    for (int j = 0; j < 32; ++j) hid[j] += xv * Ws[k * 32 + j];
  }
  float z = b2[0];
#pragma unroll
  for (int j = 0; j < 32; ++j) z += fmaxf(hid[j], 0.f) * W2s[j];
  na[n] = z;
}

__global__ void na_sum_kernel(const float* __restrict__ na, float* __restrict__ gsum) {
  __shared__ float s[4];
  float acc = 0.f;
  for (int i = blockIdx.x * blockDim.x + threadIdx.x; i < NN; i += gridDim.x * blockDim.x)
    acc += expf(na[i]);
  for (int o = 32; o; o >>= 1) acc += __shfl_xor(acc, o, 64);
  int wid = threadIdx.x >> 6, lane = threadIdx.x & 63;
  if (lane == 0) s[wid] = acc;
  __syncthreads();
  if (threadIdx.x == 0) atomicAdd(gsum, s[0] + s[1] + s[2] + s[3]);
}

__global__ void na_write_kernel(const float* __restrict__ na, const float* __restrict__ gsum,
                                float* __restrict__ out) {
  int n = blockIdx.x * blockDim.x + threadIdx.x;
  if (n >= NN) return;
  out[n] = expf(na[n]) / gsum[0];
}

// ---------------- pooling (batch sorted -> binary search ranges) ----------------
__global__ void pool_kernel(const float* __restrict__ x3, const int* __restrict__ batch,
                            float* __restrict__ psum, float* __restrict__ pmax,
                            float* __restrict__ pcnt) {
  int b = blockIdx.x;
  int lane = threadIdx.x & 63, wid = threadIdx.x >> 6;
  int lo = 0, hi = NN;
  while (lo < hi) { int m = (lo + hi) >> 1; if (batch[m] < b) lo = m + 1; else hi = m; }
  int start = lo;
  lo = start; hi = NN;
  while (lo < hi) { int m = (lo + hi) >> 1; if (batch[m] < b + 1) lo = m + 1; else hi = m; }
  int end = lo;
  float acc = 0.f, mx = -INFINITY;
  for (int n = start + wid; n < end; n += 4) {
    float v = x3[(size_t)n * 64 + lane];
    acc += v;
    mx = fmaxf(mx, v);
  }
  __shared__ float ssum[4][64], smax[4][64];
  ssum[wid][lane] = acc;
  smax[wid][lane] = mx;
  __syncthreads();
  if (wid == 0) {
    acc = ssum[0][lane] + ssum[1][lane] + ssum[2][lane] + ssum[3][lane];
    mx = fmaxf(fmaxf(smax[0][lane], smax[1][lane]), fmaxf(smax[2][lane], smax[3][lane]));
    psum[b * 64 + lane] = acc;
    pmax[b * 64 + lane] = mx;
    if (lane == 0) pcnt[b] = (float)(end - start);
  }
}

// ---------------- graph classifier ----------------
__global__ void cls_kernel(const float* __restrict__ psum, const float* __restrict__ pmax,
                           const float* __restrict__ pcnt, const float* __restrict__ Wc1,
                           const float* __restrict__ bc1, const float* __restrict__ Wc2,
                           const float* __restrict__ bc2, const float* __restrict__ Wc3,
                           const float* __restrict__ bc3, float* __restrict__ out) {
  __shared__ float g[128], h1[128], h2[64];
  int b = blockIdx.x, t = threadIdx.x;
  float cnt = pcnt[b];
  if (t < 64) {
    g[t] = (cnt > 0.f) ? psum[b * 64 + t] / fmaxf(cnt, 1.f) : 0.f;
    g[64 + t] = (cnt > 0.f) ? pmax[b * 64 + t] : 0.f;
  }
  __syncthreads();
  float v = bc1[t];
  for (int k = 0; k < 128; ++k) v += g[k] * Wc1[k * 128 + t];
  h1[t] = fmaxf(v, 0.f);
  __syncthreads();
  if (t < 64) {
    float v2 = bc2[t];
    for (int k = 0; k < 128; ++k) v2 += h1[k] * Wc2[k * 64 + t];
    h2[t] = fmaxf(v2, 0.f);
  }
  __syncthreads();
  if (t == 0) {
    float z = bc3[0];
    for (int k = 0; k < 64; ++k) z += h2[k] * Wc3[k];
    out[b] = 1.f / (1.f + expf(-z));
  }
}

extern "C" void kernel_launch(void* const* d_in, const int* in_sizes, int n_in,
                              void* d_out, int out_size, void* d_ws, size_t ws_size,
                              hipStream_t stream) {
  const float* x    = (const float*)d_in[0];
  const int*   ei   = (const int*)d_in[1];
  const int*   batch= (const int*)d_in[2];
  const float* W1 = (const float*)d_in[3];
  const float* aS1= (const float*)d_in[4];
  const float* aD1= (const float*)d_in[5];
  const float* b1 = (const float*)d_in[6];
  const float* W2 = (const float*)d_in[7];
  const float* aS2= (const float*)d_in[8];
  const float* aD2= (const float*)d_in[9];
  const float* b2 = (const float*)d_in[10];
  const float* W3 = (const float*)d_in[11];
  const float* aS3= (const float*)d_in[12];
  const float* aD3= (const float*)d_in[13];
  const float* b3 = (const float*)d_in[14];
  const float* Wna1=(const float*)d_in[15];
  const float* bna1=(const float*)d_in[16];
  const float* Wna2=(const float*)d_in[17];
  const float* bna2=(const float*)d_in[18];
  const float* Wc1=(const float*)d_in[19];
  const float* bc1=(const float*)d_in[20];
  const float* Wc2=(const float*)d_in[21];
  const float* bc2=(const float*)d_in[22];
  const float* Wc3=(const float*)d_in[23];
  const float* bc3=(const float*)d_in[24];
  float* out = (float*)d_out;

  // workspace carve-out (~121 MB)
  char* w = (char*)d_ws;
  size_t off = 0;
  auto alloc = [&](size_t bytes) {
    void* p = w + off;
    off = (off + bytes + 255) & ~(size_t)255;
    return p;
  };
  float* buf0 = (float*)alloc((size_t)NN * 256 * 4);
  float* buf1 = (float*)alloc((size_t)NN * 256 * 4);
  float* x3   = (float*)alloc((size_t)NN * 64 * 4);
  float* asb  = (float*)alloc((size_t)NN * 4 * 4);
  float* adb  = (float*)alloc((size_t)NN * 4 * 4);
  float* nab  = (float*)alloc((size_t)NN * 4);
  int* rowp = (int*)alloc((size_t)(NN + 1) * 4);
  int* cntb = (int*)alloc((size_t)NN * 4);
  int* curb = (int*)alloc((size_t)NN * 4);
  int* colb = (int*)alloc((size_t)ETOT * 4);
  int* part = (int*)alloc(98 * 4);
  float* gsum = (float*)alloc(4);
  float* psum = (float*)alloc((size_t)BB * 64 * 4);
  float* pmax = (float*)alloc((size_t)BB * 64 * 4);
  float* pcnt = (float*)alloc((size_t)BB * 4);
  (void)ws_size; (void)in_sizes; (void)n_in; (void)out_size;

  hipMemsetAsync(cntb, 0, (size_t)NN * 4, stream);
  hipMemsetAsync(curb, 0, (size_t)NN * 4, stream);
  hipMemsetAsync(gsum, 0, 4, stream);

  // CSR by dst (self-loops appended)
  count_kernel<<<(ETOT + 255) / 256, 256, 0, stream>>>(ei, cntb);
  scan1_kernel<<<98, 512, 0, stream>>>(cntb, rowp, part);
  scan2_kernel<<<1, 1, 0, stream>>>(part, rowp);
  scan3_kernel<<<98, 512, 0, stream>>>(rowp, part);
  fill_kernel<<<(ETOT + 255) / 256, 256, 0, stream>>>(ei, rowp, curb, colb);

  // layer 1: 15 -> 256
  gemm_kernel<<<dim3(782, 4), 256, 0, stream>>>(x, W1, buf0, NN, 15, 256);
  score_kernel<4><<<12500, 256, 0, stream>>>(buf0, aS1, aD1, asb, adb);
  agg_kernel<4><<<12500, 256, 0, stream>>>(buf0, asb, adb, rowp, colb, b1, buf1);
  // layer 2: 256 -> 256
  gemm_kernel<<<dim3(782, 4), 256, 0, stream>>>(buf1, W2, buf0, NN, 256, 256);
  score_kernel<4><<<12500, 256, 0, stream>>>(buf0, aS2, aD2, asb, adb);
  agg_kernel<4><<<12500, 256, 0, stream>>>(buf0, asb, adb, rowp, colb, b2, buf1);
  // layer 3: 256 -> 64
  gemm_kernel<<<dim3(782, 1), 256, 0, stream>>>(buf1, W3, buf0, NN, 256, 64);
  score_kernel<1><<<12500, 256, 0, stream>>>(buf0, aS3, aD3, asb, adb);
  agg_kernel<1><<<12500, 256, 0, stream>>>(buf0, asb, adb, rowp, colb, b3, x3);

  // node attention softmax over all N
  na_kernel<<<(NN + 255) / 256, 256, 0, stream>>>(x3, Wna1, bna1, Wna2, bna2, nab);
  na_sum_kernel<<<196, 256, 0, stream>>>(nab, gsum);
  na_write_kernel<<<(NN + 255) / 256, 256, 0, stream>>>(nab, gsum, out + BB);

  // pooling + classifier
  pool_kernel<<<BB, 256, 0, stream>>>(x3, batch, psum, pmax, pcnt);
  cls_kernel<<<BB, 128, 0, stream>>>(psum, pmax, pcnt, Wc1, bc1, Wc2, bc2, Wc3, bc3, out);
}

// Round 2
// 744.984 us; speedup vs baseline: 1.1050x; 1.1050x over previous
//
#include <hip/hip_runtime.h>
#include <math.h>

#define NN 50000
#define EE 800000
#define ETOT (EE + NN)
#define BB 50

__device__ __forceinline__ float readlane_f(float v, int l) {
  return __int_as_float(__builtin_amdgcn_readlane(__float_as_int(v), l));
}

// ---------------- CSR build ----------------
__global__ void count_kernel(const int* __restrict__ ei, int* __restrict__ cnt) {
  int e = blockIdx.x * blockDim.x + threadIdx.x;
  if (e >= ETOT) return;
  int d = (e < EE) ? ei[EE + e] : (e - EE);
  atomicAdd(&cnt[d], 1);
}

__global__ void scan1_kernel(const int* __restrict__ cnt, int* __restrict__ rowp,
                             int* __restrict__ part) {
  __shared__ int s[512];
  int t = threadIdx.x;
  int i = blockIdx.x * 512 + t;
  int v = (i < NN) ? cnt[i] : 0;
  s[t] = v;
  __syncthreads();
  for (int off = 1; off < 512; off <<= 1) {
    int add = (t >= off) ? s[t - off] : 0;
    __syncthreads();
    s[t] += add;
    __syncthreads();
  }
  if (i < NN) rowp[i] = s[t] - v;  // exclusive within block
  if (t == 511) part[blockIdx.x] = s[511];
}

__global__ void scan2_kernel(int* part, int* rowp) {
  int run = 0;
  for (int b = 0; b < 98; ++b) { int v = part[b]; part[b] = run; run += v; }
  rowp[NN] = run;  // == ETOT
}

__global__ void scan3_kernel(int* __restrict__ rowp, const int* __restrict__ part) {
  int i = blockIdx.x * 512 + threadIdx.x;
  if (i < NN) rowp[i] += part[blockIdx.x];
}

__global__ void fill_kernel(const int* __restrict__ ei, const int* __restrict__ rowp,
                            int* __restrict__ cur, int* __restrict__ col) {
  int e = blockIdx.x * blockDim.x + threadIdx.x;
  if (e >= ETOT) return;
  int s, d;
  if (e < EE) { s = ei[e]; d = ei[EE + e]; } else { s = e - EE; d = s; }
  int p = atomicAdd(&cur[d], 1);
  col[rowp[d] + p] = s;
}

// ---------------- GEMM: H = A[n,K] @ W[K,CO] ----------------
__global__ __launch_bounds__(256) void gemm_kernel(
    const float* __restrict__ A, const float* __restrict__ B,
    float* __restrict__ Cout, int n, int K, int CO) {
  __shared__ __align__(16) float AsT[16][68];
  __shared__ __align__(16) float Bs[16][68];
  int tx = threadIdx.x % 16, ty = threadIdx.x / 16;
  int r0 = blockIdx.x * 64, c0 = blockIdx.y * 64;
  float acc[4][4];
#pragma unroll
  for (int i = 0; i < 4; ++i)
#pragma unroll
    for (int j = 0; j < 4; ++j) acc[i][j] = 0.f;

  for (int k0 = 0; k0 < K; k0 += 16) {
    int ka = threadIdx.x % 16, ra0 = threadIdx.x / 16;
    int cb = threadIdx.x % 64, kb0 = threadIdx.x / 64;
#pragma unroll
    for (int p = 0; p < 4; ++p) {
      int r = ra0 + p * 16;
      int gr = r0 + r, gk = k0 + ka;
      float v = 0.f;
      if (gr < n && gk < K) v = A[(size_t)gr * K + gk];
      AsT[ka][r] = v;
      int k = kb0 + p * 4;
      int gk2 = k0 + k, gc = c0 + cb;
      float v2 = 0.f;
      if (gk2 < K && gc < CO) v2 = B[(size_t)gk2 * CO + gc];
      Bs[k][cb] = v2;
    }
    __syncthreads();
#pragma unroll
    for (int kk = 0; kk < 16; ++kk) {
      float4 a4 = *(const float4*)&AsT[kk][ty * 4];
      float4 b4 = *(const float4*)&Bs[kk][tx * 4];
      float a[4] = {a4.x, a4.y, a4.z, a4.w};
      float b[4] = {b4.x, b4.y, b4.z, b4.w};
#pragma unroll
      for (int i = 0; i < 4; ++i)
#pragma unroll
        for (int j = 0; j < 4; ++j) acc[i][j] += a[i] * b[j];
    }
    __syncthreads();
  }
#pragma unroll
  for (int i = 0; i < 4; ++i) {
    int gr = r0 + ty * 4 + i;
    if (gr < n) {
      float4 o = make_float4(acc[i][0], acc[i][1], acc[i][2], acc[i][3]);
      *(float4*)&Cout[(size_t)gr * CO + c0 + tx * 4] = o;
    }
  }
}

// ---------------- per-node attention scores ----------------
template <int H>
__global__ void score_kernel(const float* __restrict__ h, const float* __restrict__ aS,
                             const float* __restrict__ aD, float* __restrict__ as_o,
                             float* __restrict__ ad_o) {
  const int CT = H * 64;
  int wid = threadIdx.x >> 6, lane = threadIdx.x & 63;
  int n = blockIdx.x * (blockDim.x >> 6) + wid;
  if (n >= NN) return;
  float ps[H], pd[H];
#pragma unroll
  for (int j = 0; j < H; ++j) {
    float hv = h[(size_t)n * CT + lane + 64 * j];
    ps[j] = hv * aS[lane + 64 * j];
    pd[j] = hv * aD[lane + 64 * j];
  }
#pragma unroll
  for (int j = 0; j < H; ++j) {
    for (int o = 32; o; o >>= 1) {
      ps[j] += __shfl_xor(ps[j], o, 64);
      pd[j] += __shfl_xor(pd[j], o, 64);
    }
  }
  if (lane == 0) {
#pragma unroll
    for (int j = 0; j < H; ++j) {
      as_o[(size_t)n * H + j] = ps[j];
      ad_o[(size_t)n * H + j] = pd[j];
    }
  }
}

// ---------------- single-pass softmax-aggregate, H=4 ----------------
// out[d] = (sum_e ex_e * h[src_e]) / (sum_e ex_e); divide once at the end.
// Lane owns channels [4*lane, 4*lane+3] (all in head lane>>4). Per-edge ex[4]
// computed once (lane-parallel chunk), shared via per-wave LDS slab.
__global__ __launch_bounds__(256) void agg4_kernel(
    const float* __restrict__ h, const float* __restrict__ as_i,
    const float* __restrict__ ad_i, const int* __restrict__ rowp,
    const int* __restrict__ col, const float* __restrict__ bias,
    float* __restrict__ xo) {
  __shared__ float exs[4][64][4];  // [wave][edge-slot][head]
  int wid = threadIdx.x >> 6, lane = threadIdx.x & 63;
  int d = blockIdx.x * 4 + wid;
  int rp0 = rowp[d], deg = rowp[d + 1] - rp0;
  float4 add = *(const float4*)&ad_i[(size_t)d * 4];
  int hj = lane >> 4;  // head index for this lane's 4 channels
  float acc0 = 0.f, acc1 = 0.f, acc2 = 0.f, acc3 = 0.f;
  float den0 = 0.f, den1 = 0.f, den2 = 0.f, den3 = 0.f;

  for (int base = 0; base < deg; base += 64) {
    int i = base + lane;
    bool valid = i < deg;
    int s = valid ? col[rp0 + i] : 0;
    float4 asv = *(const float4*)&as_i[(size_t)s * 4];
    float e0 = asv.x + add.x, e1 = asv.y + add.y, e2 = asv.z + add.z, e3 = asv.w + add.w;
    e0 = (e0 > 0.f) ? e0 : 0.2f * e0;
    e1 = (e1 > 0.f) ? e1 : 0.2f * e1;
    e2 = (e2 > 0.f) ? e2 : 0.2f * e2;
    e3 = (e3 > 0.f) ? e3 : 0.2f * e3;
    float x0 = valid ? __expf(e0) : 0.f;
    float x1 = valid ? __expf(e1) : 0.f;
    float x2 = valid ? __expf(e2) : 0.f;
    float x3 = valid ? __expf(e3) : 0.f;
    den0 += x0; den1 += x1; den2 += x2; den3 += x3;
    *(float4*)&exs[wid][lane][0] = make_float4(x0, x1, x2, x3);
    __threadfence_block();  // order ds_write before the broadcast ds_reads
    int cnt = min(64, deg - base);
    for (int k = 0; k < cnt; ++k) {
      int sk = __builtin_amdgcn_readlane(s, k);  // uniform -> SGPR base
      float exk = exs[wid][k][hj];               // broadcast LDS read
      float4 hv = *(const float4*)&h[(size_t)sk * 256 + lane * 4];
      acc0 += exk * hv.x;
      acc1 += exk * hv.y;
      acc2 += exk * hv.z;
      acc3 += exk * hv.w;
    }
  }
#pragma unroll
  for (int o = 32; o; o >>= 1) {
    den0 += __shfl_xor(den0, o, 64);
    den1 += __shfl_xor(den1, o, 64);
    den2 += __shfl_xor(den2, o, 64);
    den3 += __shfl_xor(den3, o, 64);
  }
  float den = (hj == 0) ? den0 : (hj == 1) ? den1 : (hj == 2) ? den2 : den3;
  float inv = 1.f / den;
  float4 bv = *(const float4*)&bias[lane * 4];
  float v0 = acc0 * inv + bv.x;
  float v1 = acc1 * inv + bv.y;
  float v2 = acc2 * inv + bv.z;
  float v3 = acc3 * inv + bv.w;
  v0 = (v0 > 0.f) ? v0 : expm1f(v0);
  v1 = (v1 > 0.f) ? v1 : expm1f(v1);
  v2 = (v2 > 0.f) ? v2 : expm1f(v2);
  v3 = (v3 > 0.f) ? v3 : expm1f(v3);
  *(float4*)&xo[(size_t)d * 256 + lane * 4] = make_float4(v0, v1, v2, v3);
}

// ---------------- single-pass softmax-aggregate, H=1 ----------------
__global__ __launch_bounds__(256) void agg1_kernel(
    const float* __restrict__ h, const float* __restrict__ as_i,
    const float* __restrict__ ad_i, const int* __restrict__ rowp,
    const int* __restrict__ col, const float* __restrict__ bias,
    float* __restrict__ xo) {
  int wid = threadIdx.x >> 6, lane = threadIdx.x & 63;
  int d = blockIdx.x * 4 + wid;
  int rp0 = rowp[d], deg = rowp[d + 1] - rp0;
  float add = ad_i[d];
  float acc = 0.f, den = 0.f;
  for (int base = 0; base < deg; base += 64) {
    int i = base + lane;
    bool valid = i < deg;
    int s = valid ? col[rp0 + i] : 0;
    float e = as_i[s] + add;
    e = (e > 0.f) ? e : 0.2f * e;
    float ex = valid ? __expf(e) : 0.f;
    den += ex;
    int cnt = min(64, deg - base);
    for (int k = 0; k < cnt; ++k) {
      int sk = __builtin_amdgcn_readlane(s, k);
      float exk = readlane_f(ex, k);
      acc += exk * h[(size_t)sk * 64 + lane];
    }
  }
#pragma unroll
  for (int o = 32; o; o >>= 1) den += __shfl_xor(den, o, 64);
  float v = acc / den + bias[lane];
  v = (v > 0.f) ? v : expm1f(v);
  xo[(size_t)d * 64 + lane] = v;
}

// ---------------- node-attention MLP ----------------
__global__ void na_kernel(const float* __restrict__ x3, const float* __restrict__ W1,
                          const float* __restrict__ b1, const float* __restrict__ W2,
                          const float* __restrict__ b2, float* __restrict__ na) {
  __shared__ float Ws[64 * 32];
  __shared__ float W2s[32];
  for (int i = threadIdx.x; i < 2048; i += blockDim.x) Ws[i] = W1[i];
  if (threadIdx.x < 32) W2s[threadIdx.x] = W2[threadIdx.x];
  __syncthreads();
  int n = blockIdx.x * blockDim.x + threadIdx.x;
  if (n >= NN) return;
  float hid[32];
#pragma unroll
  for (int j = 0; j < 32; ++j) hid[j] = b1[j];
  for (int k = 0; k < 64; ++k) {
    float xv = x3[(size_t)n * 64 + k];
#pragma unroll
    for (int j = 0; j < 32; ++j) hid[j] += xv * Ws[k * 32 + j];
  }
  float z = b2[0];
#pragma unroll
  for (int j = 0; j < 32; ++j) z += fmaxf(hid[j], 0.f) * W2s[j];
  na[n] = z;
}

__global__ void na_sum_kernel(const float* __restrict__ na, float* __restrict__ gsum) {
  __shared__ float s[4];
  float acc = 0.f;
  for (int i = blockIdx.x * blockDim.x + threadIdx.x; i < NN; i += gridDim.x * blockDim.x)
    acc += expf(na[i]);
  for (int o = 32; o; o >>= 1) acc += __shfl_xor(acc, o, 64);
  int wid = threadIdx.x >> 6, lane = threadIdx.x & 63;
  if (lane == 0) s[wid] = acc;
  __syncthreads();
  if (threadIdx.x == 0) atomicAdd(gsum, s[0] + s[1] + s[2] + s[3]);
}

__global__ void na_write_kernel(const float* __restrict__ na, const float* __restrict__ gsum,
                                float* __restrict__ out) {
  int n = blockIdx.x * blockDim.x + threadIdx.x;
  if (n >= NN) return;
  out[n] = expf(na[n]) / gsum[0];
}

// ---------------- pooling (batch sorted -> binary search ranges) ----------------
__global__ void pool_kernel(const float* __restrict__ x3, const int* __restrict__ batch,
                            float* __restrict__ psum, float* __restrict__ pmax,
                            float* __restrict__ pcnt) {
  int b = blockIdx.x;
  int lane = threadIdx.x & 63, wid = threadIdx.x >> 6;
  int lo = 0, hi = NN;
  while (lo < hi) { int m = (lo + hi) >> 1; if (batch[m] < b) lo = m + 1; else hi = m; }
  int start = lo;
  lo = start; hi = NN;
  while (lo < hi) { int m = (lo + hi) >> 1; if (batch[m] < b + 1) lo = m + 1; else hi = m; }
  int end = lo;
  float acc = 0.f, mx = -INFINITY;
  for (int n = start + wid; n < end; n += 4) {
    float v = x3[(size_t)n * 64 + lane];
    acc += v;
    mx = fmaxf(mx, v);
  }
  __shared__ float ssum[4][64], smax[4][64];
  ssum[wid][lane] = acc;
  smax[wid][lane] = mx;
  __syncthreads();
  if (wid == 0) {
    acc = ssum[0][lane] + ssum[1][lane] + ssum[2][lane] + ssum[3][lane];
    mx = fmaxf(fmaxf(smax[0][lane], smax[1][lane]), fmaxf(smax[2][lane], smax[3][lane]));
    psum[b * 64 + lane] = acc;
    pmax[b * 64 + lane] = mx;
    if (lane == 0) pcnt[b] = (float)(end - start);
  }
}

// ---------------- graph classifier ----------------
__global__ void cls_kernel(const float* __restrict__ psum, const float* __restrict__ pmax,
                           const float* __restrict__ pcnt, const float* __restrict__ Wc1,
                           const float* __restrict__ bc1, const float* __restrict__ Wc2,
                           const float* __restrict__ bc2, const float* __restrict__ Wc3,
                           const float* __restrict__ bc3, float* __restrict__ out) {
  __shared__ float g[128], h1[128], h2[64];
  int b = blockIdx.x, t = threadIdx.x;
  float cnt = pcnt[b];
  if (t < 64) {
    g[t] = (cnt > 0.f) ? psum[b * 64 + t] / fmaxf(cnt, 1.f) : 0.f;
    g[64 + t] = (cnt > 0.f) ? pmax[b * 64 + t] : 0.f;
  }
  __syncthreads();
  float v = bc1[t];
  for (int k = 0; k < 128; ++k) v += g[k] * Wc1[k * 128 + t];
  h1[t] = fmaxf(v, 0.f);
  __syncthreads();
  if (t < 64) {
    float v2 = bc2[t];
    for (int k = 0; k < 128; ++k) v2 += h1[k] * Wc2[k * 64 + t];
    h2[t] = fmaxf(v2, 0.f);
  }
  __syncthreads();
  if (t == 0) {
    float z = bc3[0];
    for (int k = 0; k < 64; ++k) z += h2[k] * Wc3[k];
    out[b] = 1.f / (1.f + expf(-z));
  }
}

extern "C" void kernel_launch(void* const* d_in, const int* in_sizes, int n_in,
                              void* d_out, int out_size, void* d_ws, size_t ws_size,
                              hipStream_t stream) {
  const float* x    = (const float*)d_in[0];
  const int*   ei   = (const int*)d_in[1];
  const int*   batch= (const int*)d_in[2];
  const float* W1 = (const float*)d_in[3];
  const float* aS1= (const float*)d_in[4];
  const float* aD1= (const float*)d_in[5];
  const float* b1 = (const float*)d_in[6];
  const float* W2 = (const float*)d_in[7];
  const float* aS2= (const float*)d_in[8];
  const float* aD2= (const float*)d_in[9];
  const float* b2 = (const float*)d_in[10];
  const float* W3 = (const float*)d_in[11];
  const float* aS3= (const float*)d_in[12];
  const float* aD3= (const float*)d_in[13];
  const float* b3 = (const float*)d_in[14];
  const float* Wna1=(const float*)d_in[15];
  const float* bna1=(const float*)d_in[16];
  const float* Wna2=(const float*)d_in[17];
  const float* bna2=(const float*)d_in[18];
  const float* Wc1=(const float*)d_in[19];
  const float* bc1=(const float*)d_in[20];
  const float* Wc2=(const float*)d_in[21];
  const float* bc2=(const float*)d_in[22];
  const float* Wc3=(const float*)d_in[23];
  const float* bc3=(const float*)d_in[24];
  float* out = (float*)d_out;

  // workspace carve-out (~121 MB)
  char* w = (char*)d_ws;
  size_t off = 0;
  auto alloc = [&](size_t bytes) {
    void* p = w + off;
    off = (off + bytes + 255) & ~(size_t)255;
    return p;
  };
  float* buf0 = (float*)alloc((size_t)NN * 256 * 4);
  float* buf1 = (float*)alloc((size_t)NN * 256 * 4);
  float* x3   = (float*)alloc((size_t)NN * 64 * 4);
  float* asb  = (float*)alloc((size_t)NN * 4 * 4);
  float* adb  = (float*)alloc((size_t)NN * 4 * 4);
  float* nab  = (float*)alloc((size_t)NN * 4);
  int* rowp = (int*)alloc((size_t)(NN + 1) * 4);
  int* cntb = (int*)alloc((size_t)NN * 4);
  int* curb = (int*)alloc((size_t)NN * 4);
  int* colb = (int*)alloc((size_t)ETOT * 4);
  int* part = (int*)alloc(98 * 4);
  float* gsum = (float*)alloc(4);
  float* psum = (float*)alloc((size_t)BB * 64 * 4);
  float* pmax = (float*)alloc((size_t)BB * 64 * 4);
  float* pcnt = (float*)alloc((size_t)BB * 4);
  (void)ws_size; (void)in_sizes; (void)n_in; (void)out_size;

  hipMemsetAsync(cntb, 0, (size_t)NN * 4, stream);
  hipMemsetAsync(curb, 0, (size_t)NN * 4, stream);
  hipMemsetAsync(gsum, 0, 4, stream);

  // CSR by dst (self-loops appended)
  count_kernel<<<(ETOT + 255) / 256, 256, 0, stream>>>(ei, cntb);
  scan1_kernel<<<98, 512, 0, stream>>>(cntb, rowp, part);
  scan2_kernel<<<1, 1, 0, stream>>>(part, rowp);
  scan3_kernel<<<98, 512, 0, stream>>>(rowp, part);
  fill_kernel<<<(ETOT + 255) / 256, 256, 0, stream>>>(ei, rowp, curb, colb);

  // layer 1: 15 -> 256
  gemm_kernel<<<dim3(782, 4), 256, 0, stream>>>(x, W1, buf0, NN, 15, 256);
  score_kernel<4><<<12500, 256, 0, stream>>>(buf0, aS1, aD1, asb, adb);
  agg4_kernel<<<12500, 256, 0, stream>>>(buf0, asb, adb, rowp, colb, b1, buf1);
  // layer 2: 256 -> 256
  gemm_kernel<<<dim3(782, 4), 256, 0, stream>>>(buf1, W2, buf0, NN, 256, 256);
  score_kernel<4><<<12500, 256, 0, stream>>>(buf0, aS2, aD2, asb, adb);
  agg4_kernel<<<12500, 256, 0, stream>>>(buf0, asb, adb, rowp, colb, b2, buf1);
  // layer 3: 256 -> 64
  gemm_kernel<<<dim3(782, 1), 256, 0, stream>>>(buf1, W3, buf0, NN, 256, 64);
  score_kernel<1><<<12500, 256, 0, stream>>>(buf0, aS3, aD3, asb, adb);
  agg1_kernel<<<12500, 256, 0, stream>>>(buf0, asb, adb, rowp, colb, b3, x3);

  // node attention softmax over all N
  na_kernel<<<(NN + 255) / 256, 256, 0, stream>>>(x3, Wna1, bna1, Wna2, bna2, nab);
  na_sum_kernel<<<196, 256, 0, stream>>>(nab, gsum);
  na_write_kernel<<<(NN + 255) / 256, 256, 0, stream>>>(nab, gsum, out + BB);

  // pooling + classifier
  pool_kernel<<<BB, 256, 0, stream>>>(x3, batch, psum, pmax, pcnt);
  cls_kernel<<<BB, 128, 0, stream>>>(psum, pmax, pcnt, Wc1, bc1, Wc2, bc2, Wc3, bc3, out);
}

// Round 3
// 538.971 us; speedup vs baseline: 1.5273x; 1.3822x over previous
//
#include <hip/hip_runtime.h>
#include <math.h>

#define NN 50000
#define EE 800000
#define ETOT (EE + NN)
#define BB 50

typedef unsigned short u16;
typedef __attribute__((ext_vector_type(8))) short short8;
typedef __attribute__((ext_vector_type(4))) float floatx4;

__device__ __forceinline__ float b2f(u16 u) {
  return __int_as_float(((int)u) << 16);
}
__device__ __forceinline__ u16 f2b(float f) {
  unsigned u = __float_as_uint(f);
  unsigned r = (u + 0x7fffu + ((u >> 16) & 1u)) >> 16;
  return (u16)r;
}
__device__ __forceinline__ float readlane_f(float v, int l) {
  return __int_as_float(__builtin_amdgcn_readlane(__float_as_int(v), l));
}

// ---------------- CSR build ----------------
__global__ void count_kernel(const int* __restrict__ ei, int* __restrict__ cnt) {
  int e = blockIdx.x * blockDim.x + threadIdx.x;
  if (e >= ETOT) return;
  int d = (e < EE) ? ei[EE + e] : (e - EE);
  atomicAdd(&cnt[d], 1);
}

__global__ void scan1_kernel(const int* __restrict__ cnt, int* __restrict__ rowp,
                             int* __restrict__ part) {
  __shared__ int s[512];
  int t = threadIdx.x;
  int i = blockIdx.x * 512 + t;
  int v = (i < NN) ? cnt[i] : 0;
  s[t] = v;
  __syncthreads();
  for (int off = 1; off < 512; off <<= 1) {
    int add = (t >= off) ? s[t - off] : 0;
    __syncthreads();
    s[t] += add;
    __syncthreads();
  }
  if (i < NN) rowp[i] = s[t] - v;  // exclusive within block
  if (t == 511) part[blockIdx.x] = s[511];
}

__global__ void scan2_kernel(int* part, int* rowp) {
  int run = 0;
  for (int b = 0; b < 98; ++b) { int v = part[b]; part[b] = run; run += v; }
  rowp[NN] = run;  // == ETOT
}

__global__ void scan3_kernel(int* __restrict__ rowp, const int* __restrict__ part) {
  int i = blockIdx.x * 512 + threadIdx.x;
  if (i < NN) rowp[i] += part[blockIdx.x];
}

__global__ void fill_kernel(const int* __restrict__ ei, const int* __restrict__ rowp,
                            int* __restrict__ cur, int* __restrict__ col) {
  int e = blockIdx.x * blockDim.x + threadIdx.x;
  if (e >= ETOT) return;
  int s, d;
  if (e < EE) { s = ei[e]; d = ei[EE + e]; } else { s = e - EE; d = s; }
  int p = atomicAdd(&cur[d], 1);
  col[rowp[d] + p] = s;
}

// ---------------- dtype prep ----------------
__global__ void convx_kernel(const float* __restrict__ x, u16* __restrict__ xb) {
  int i = blockIdx.x * 256 + threadIdx.x;  // over NN*32 (K padded 15->32)
  if (i >= NN * 32) return;
  int n = i >> 5, c = i & 31;
  xb[i] = (c < 15) ? f2b(x[n * 15 + c]) : (u16)0;
}

// Wt[n][k] = W[k][n] in bf16, K padded with zeros
__global__ void convwT_kernel(const float* __restrict__ W, u16* __restrict__ Wt,
                              int Kreal, int Kp, int Ncols) {
  int i = blockIdx.x * 256 + threadIdx.x;  // over Ncols*Kp
  if (i >= Ncols * Kp) return;
  int n = i / Kp, k = i - n * Kp;
  Wt[i] = (k < Kreal) ? f2b(W[(size_t)k * Ncols + n]) : (u16)0;
}

// ---------------- bf16 MFMA GEMM: C[M,N] = A[M,K] @ Bt[N,K]^T ----------------
// BM=128, BN=64, BK=32. 4 waves as 2x2; each wave 64x32 out (4x2 mfma frags).
__global__ __launch_bounds__(256) void gemm_bf16_kernel(
    const u16* __restrict__ A, const u16* __restrict__ Bt, u16* __restrict__ C,
    int M, int K, int N) {
  __shared__ u16 Al[128][40];
  __shared__ u16 Bl[64][40];
  int R0 = blockIdx.x * 128, C0 = blockIdx.y * 64;
  int wid = threadIdx.x >> 6, lane = threadIdx.x & 63;
  int wr = (wid >> 1) * 64, wc = (wid & 1) * 32;
  int lrow = lane & 15, lk8 = (lane >> 4) * 8;
  floatx4 acc[4][2];
#pragma unroll
  for (int i = 0; i < 4; ++i)
#pragma unroll
    for (int j = 0; j < 2; ++j) acc[i][j] = (floatx4){0.f, 0.f, 0.f, 0.f};

  for (int k0 = 0; k0 < K; k0 += 32) {
#pragma unroll
    for (int c = threadIdx.x; c < 1024; c += 256) {
      int r = c >> 3, off = (c & 7) * 4;
      int gr = R0 + r;
      ushort4 va = make_ushort4(0, 0, 0, 0);
      if (gr < M) va = *(const ushort4*)&A[(size_t)gr * K + k0 + off];
      *(ushort4*)&Al[r][off] = va;
      if (c < 512)
        *(ushort4*)&Bl[r][off] = *(const ushort4*)&Bt[(size_t)(C0 + r) * K + k0 + off];
    }
    __syncthreads();
    short8 a[4], b[2];
#pragma unroll
    for (int i = 0; i < 4; ++i) a[i] = *(const short8*)&Al[wr + i * 16 + lrow][lk8];
#pragma unroll
    for (int j = 0; j < 2; ++j) b[j] = *(const short8*)&Bl[wc + j * 16 + lrow][lk8];
#pragma unroll
    for (int i = 0; i < 4; ++i)
#pragma unroll
      for (int j = 0; j < 2; ++j)
        acc[i][j] = __builtin_amdgcn_mfma_f32_16x16x32_bf16(a[i], b[j], acc[i][j], 0, 0, 0);
    __syncthreads();
  }
  int rq = (lane >> 4) * 4;
#pragma unroll
  for (int i = 0; i < 4; ++i)
#pragma unroll
    for (int j = 0; j < 2; ++j)
#pragma unroll
      for (int q = 0; q < 4; ++q) {
        int gr = R0 + wr + i * 16 + rq + q;
        if (gr < M) C[(size_t)gr * N + C0 + wc + j * 16 + lrow] = f2b(acc[i][j][q]);
      }
}

// ---------------- per-node attention scores (bf16 h) ----------------
template <int H>
__global__ void score_kernel(const u16* __restrict__ h, const float* __restrict__ aS,
                             const float* __restrict__ aD, float* __restrict__ as_o,
                             float* __restrict__ ad_o) {
  const int CT = H * 64;
  int wid = threadIdx.x >> 6, lane = threadIdx.x & 63;
  int n = blockIdx.x * (blockDim.x >> 6) + wid;
  if (n >= NN) return;
  float ps[H], pd[H];
#pragma unroll
  for (int j = 0; j < H; ++j) {
    float hv = b2f(h[(size_t)n * CT + lane + 64 * j]);
    ps[j] = hv * aS[lane + 64 * j];
    pd[j] = hv * aD[lane + 64 * j];
  }
#pragma unroll
  for (int j = 0; j < H; ++j) {
    for (int o = 32; o; o >>= 1) {
      ps[j] += __shfl_xor(ps[j], o, 64);
      pd[j] += __shfl_xor(pd[j], o, 64);
    }
  }
  if (lane == 0) {
#pragma unroll
    for (int j = 0; j < H; ++j) {
      as_o[(size_t)n * H + j] = ps[j];
      ad_o[(size_t)n * H + j] = pd[j];
    }
  }
}

// ---------------- single-pass softmax-aggregate, H=4, bf16 h -> bf16 out ----------------
__global__ __launch_bounds__(256) void agg4_kernel(
    const u16* __restrict__ h, const float* __restrict__ as_i,
    const float* __restrict__ ad_i, const int* __restrict__ rowp,
    const int* __restrict__ col, const float* __restrict__ bias,
    u16* __restrict__ xo) {
  __shared__ float exs[4][64][4];  // [wave][edge-slot][head]
  int wid = threadIdx.x >> 6, lane = threadIdx.x & 63;
  int d = blockIdx.x * 4 + wid;
  int rp0 = rowp[d], deg = rowp[d + 1] - rp0;
  float4 add = *(const float4*)&ad_i[(size_t)d * 4];
  int hj = lane >> 4;  // head of this lane's 4 channels
  float acc0 = 0.f, acc1 = 0.f, acc2 = 0.f, acc3 = 0.f;
  float den0 = 0.f, den1 = 0.f, den2 = 0.f, den3 = 0.f;
  const ushort4* hq = (const ushort4*)h;  // 64 ushort4 per 256-ch row

  for (int base = 0; base < deg; base += 64) {
    int i = base + lane;
    bool valid = i < deg;
    int s = valid ? col[rp0 + i] : 0;
    float4 asv = *(const float4*)&as_i[(size_t)s * 4];
    float e0 = asv.x + add.x, e1 = asv.y + add.y, e2 = asv.z + add.z, e3 = asv.w + add.w;
    e0 = (e0 > 0.f) ? e0 : 0.2f * e0;
    e1 = (e1 > 0.f) ? e1 : 0.2f * e1;
    e2 = (e2 > 0.f) ? e2 : 0.2f * e2;
    e3 = (e3 > 0.f) ? e3 : 0.2f * e3;
    float x0 = valid ? __expf(e0) : 0.f;
    float x1 = valid ? __expf(e1) : 0.f;
    float x2 = valid ? __expf(e2) : 0.f;
    float x3 = valid ? __expf(e3) : 0.f;
    den0 += x0; den1 += x1; den2 += x2; den3 += x3;
    *(float4*)&exs[wid][lane][0] = make_float4(x0, x1, x2, x3);
    __threadfence_block();  // order ds_write before the broadcast ds_reads
    int cnt = min(64, deg - base);
#pragma unroll 2
    for (int k = 0; k < cnt; ++k) {
      int sk = __builtin_amdgcn_readlane(s, k);  // uniform -> SGPR base
      float exk = exs[wid][k][hj];               // broadcast LDS read
      ushort4 hv = hq[(size_t)sk * 64 + lane];
      acc0 += exk * b2f(hv.x);
      acc1 += exk * b2f(hv.y);
      acc2 += exk * b2f(hv.z);
      acc3 += exk * b2f(hv.w);
    }
  }
#pragma unroll
  for (int o = 32; o; o >>= 1) {
    den0 += __shfl_xor(den0, o, 64);
    den1 += __shfl_xor(den1, o, 64);
    den2 += __shfl_xor(den2, o, 64);
    den3 += __shfl_xor(den3, o, 64);
  }
  float den = (hj == 0) ? den0 : (hj == 1) ? den1 : (hj == 2) ? den2 : den3;
  float inv = 1.f / den;
  float4 bv = *(const float4*)&bias[lane * 4];
  float v0 = acc0 * inv + bv.x;
  float v1 = acc1 * inv + bv.y;
  float v2 = acc2 * inv + bv.z;
  float v3 = acc3 * inv + bv.w;
  v0 = (v0 > 0.f) ? v0 : expm1f(v0);
  v1 = (v1 > 0.f) ? v1 : expm1f(v1);
  v2 = (v2 > 0.f) ? v2 : expm1f(v2);
  v3 = (v3 > 0.f) ? v3 : expm1f(v3);
  ushort4 o4;
  o4.x = f2b(v0); o4.y = f2b(v1); o4.z = f2b(v2); o4.w = f2b(v3);
  ((ushort4*)xo)[(size_t)d * 64 + lane] = o4;
}

// ---------------- single-pass softmax-aggregate, H=1, bf16 h -> fp32 out ----------------
__global__ __launch_bounds__(256) void agg1_kernel(
    const u16* __restrict__ h, const float* __restrict__ as_i,
    const float* __restrict__ ad_i, const int* __restrict__ rowp,
    const int* __restrict__ col, const float* __restrict__ bias,
    float* __restrict__ xo) {
  int wid = threadIdx.x >> 6, lane = threadIdx.x & 63;
  int d = blockIdx.x * 4 + wid;
  int rp0 = rowp[d], deg = rowp[d + 1] - rp0;
  float add = ad_i[d];
  float acc = 0.f, den = 0.f;
  for (int base = 0; base < deg; base += 64) {
    int i = base + lane;
    bool valid = i < deg;
    int s = valid ? col[rp0 + i] : 0;
    float e = as_i[s] + add;
    e = (e > 0.f) ? e : 0.2f * e;
    float ex = valid ? __expf(e) : 0.f;
    den += ex;
    int cnt = min(64, deg - base);
#pragma unroll 2
    for (int k = 0; k < cnt; ++k) {
      int sk = __builtin_amdgcn_readlane(s, k);
      float exk = readlane_f(ex, k);
      acc += exk * b2f(h[(size_t)sk * 64 + lane]);
    }
  }
#pragma unroll
  for (int o = 32; o; o >>= 1) den += __shfl_xor(den, o, 64);
  float v = acc / den + bias[lane];
  v = (v > 0.f) ? v : expm1f(v);
  xo[(size_t)d * 64 + lane] = v;
}

// ---------------- node-attention MLP ----------------
__global__ void na_kernel(const float* __restrict__ x3, const float* __restrict__ W1,
                          const float* __restrict__ b1, const float* __restrict__ W2,
                          const float* __restrict__ b2, float* __restrict__ na) {
  __shared__ float Ws[64 * 32];
  __shared__ float W2s[32];
  for (int i = threadIdx.x; i < 2048; i += blockDim.x) Ws[i] = W1[i];
  if (threadIdx.x < 32) W2s[threadIdx.x] = W2[threadIdx.x];
  __syncthreads();
  int n = blockIdx.x * blockDim.x + threadIdx.x;
  if (n >= NN) return;
  float hid[32];
#pragma unroll
  for (int j = 0; j < 32; ++j) hid[j] = b1[j];
  for (int k = 0; k < 64; ++k) {
    float xv = x3[(size_t)n * 64 + k];
#pragma unroll
    for (int j = 0; j < 32; ++j) hid[j] += xv * Ws[k * 32 + j];
  }
  float z = b2[0];
#pragma unroll
  for (int j = 0; j < 32; ++j) z += fmaxf(hid[j], 0.f) * W2s[j];
  na[n] = z;
}

__global__ void na_sum_kernel(const float* __restrict__ na, float* __restrict__ gsum) {
  __shared__ float s[4];
  float acc = 0.f;
  for (int i = blockIdx.x * blockDim.x + threadIdx.x; i < NN; i += gridDim.x * blockDim.x)
    acc += expf(na[i]);
  for (int o = 32; o; o >>= 1) acc += __shfl_xor(acc, o, 64);
  int wid = threadIdx.x >> 6, lane = threadIdx.x & 63;
  if (lane == 0) s[wid] = acc;
  __syncthreads();
  if (threadIdx.x == 0) atomicAdd(gsum, s[0] + s[1] + s[2] + s[3]);
}

__global__ void na_write_kernel(const float* __restrict__ na, const float* __restrict__ gsum,
                                float* __restrict__ out) {
  int n = blockIdx.x * blockDim.x + threadIdx.x;
  if (n >= NN) return;
  out[n] = expf(na[n]) / gsum[0];
}

// ---------------- pooling (batch sorted -> binary search ranges) ----------------
__global__ void pool_kernel(const float* __restrict__ x3, const int* __restrict__ batch,
                            float* __restrict__ psum, float* __restrict__ pmax,
                            float* __restrict__ pcnt) {
  int b = blockIdx.x;
  int lane = threadIdx.x & 63, wid = threadIdx.x >> 6;
  int lo = 0, hi = NN;
  while (lo < hi) { int m = (lo + hi) >> 1; if (batch[m] < b) lo = m + 1; else hi = m; }
  int start = lo;
  lo = start; hi = NN;
  while (lo < hi) { int m = (lo + hi) >> 1; if (batch[m] < b + 1) lo = m + 1; else hi = m; }
  int end = lo;
  float acc = 0.f, mx = -INFINITY;
  for (int n = start + wid; n < end; n += 4) {
    float v = x3[(size_t)n * 64 + lane];
    acc += v;
    mx = fmaxf(mx, v);
  }
  __shared__ float ssum[4][64], smax[4][64];
  ssum[wid][lane] = acc;
  smax[wid][lane] = mx;
  __syncthreads();
  if (wid == 0) {
    acc = ssum[0][lane] + ssum[1][lane] + ssum[2][lane] + ssum[3][lane];
    mx = fmaxf(fmaxf(smax[0][lane], smax[1][lane]), fmaxf(smax[2][lane], smax[3][lane]));
    psum[b * 64 + lane] = acc;
    pmax[b * 64 + lane] = mx;
    if (lane == 0) pcnt[b] = (float)(end - start);
  }
}

// ---------------- graph classifier ----------------
__global__ void cls_kernel(const float* __restrict__ psum, const float* __restrict__ pmax,
                           const float* __restrict__ pcnt, const float* __restrict__ Wc1,
                           const float* __restrict__ bc1, const float* __restrict__ Wc2,
                           const float* __restrict__ bc2, const float* __restrict__ Wc3,
                           const float* __restrict__ bc3, float* __restrict__ out) {
  __shared__ float g[128], h1[128], h2[64];
  int b = blockIdx.x, t = threadIdx.x;
  float cnt = pcnt[b];
  if (t < 64) {
    g[t] = (cnt > 0.f) ? psum[b * 64 + t] / fmaxf(cnt, 1.f) : 0.f;
    g[64 + t] = (cnt > 0.f) ? pmax[b * 64 + t] : 0.f;
  }
  __syncthreads();
  float v = bc1[t];
  for (int k = 0; k < 128; ++k) v += g[k] * Wc1[k * 128 + t];
  h1[t] = fmaxf(v, 0.f);
  __syncthreads();
  if (t < 64) {
    float v2 = bc2[t];
    for (int k = 0; k < 128; ++k) v2 += h1[k] * Wc2[k * 64 + t];
    h2[t] = fmaxf(v2, 0.f);
  }
  __syncthreads();
  if (t == 0) {
    float z = bc3[0];
    for (int k = 0; k < 64; ++k) z += h2[k] * Wc3[k];
    out[b] = 1.f / (1.f + expf(-z));
  }
}

extern "C" void kernel_launch(void* const* d_in, const int* in_sizes, int n_in,
                              void* d_out, int out_size, void* d_ws, size_t ws_size,
                              hipStream_t stream) {
  const float* x    = (const float*)d_in[0];
  const int*   ei   = (const int*)d_in[1];
  const int*   batch= (const int*)d_in[2];
  const float* W1 = (const float*)d_in[3];
  const float* aS1= (const float*)d_in[4];
  const float* aD1= (const float*)d_in[5];
  const float* b1 = (const float*)d_in[6];
  const float* W2 = (const float*)d_in[7];
  const float* aS2= (const float*)d_in[8];
  const float* aD2= (const float*)d_in[9];
  const float* b2 = (const float*)d_in[10];
  const float* W3 = (const float*)d_in[11];
  const float* aS3= (const float*)d_in[12];
  const float* aD3= (const float*)d_in[13];
  const float* b3 = (const float*)d_in[14];
  const float* Wna1=(const float*)d_in[15];
  const float* bna1=(const float*)d_in[16];
  const float* Wna2=(const float*)d_in[17];
  const float* bna2=(const float*)d_in[18];
  const float* Wc1=(const float*)d_in[19];
  const float* bc1=(const float*)d_in[20];
  const float* Wc2=(const float*)d_in[21];
  const float* bc2=(const float*)d_in[22];
  const float* Wc3=(const float*)d_in[23];
  const float* bc3=(const float*)d_in[24];
  float* out = (float*)d_out;

  // workspace carve-out (~62 MB)
  char* w = (char*)d_ws;
  size_t off = 0;
  auto alloc = [&](size_t bytes) {
    void* p = w + off;
    off = (off + bytes + 255) & ~(size_t)255;
    return p;
  };
  u16* xb   = (u16*)alloc((size_t)NN * 32 * 2);        // padded bf16 input
  u16* bufA = (u16*)alloc((size_t)NN * 256 * 2);       // h1 / h2 / h3
  u16* bufB = (u16*)alloc((size_t)NN * 256 * 2);       // y1 / y2 / x3(fp32)
  u16* W1t  = (u16*)alloc((size_t)256 * 32 * 2);
  u16* W2t  = (u16*)alloc((size_t)256 * 256 * 2);
  u16* W3t  = (u16*)alloc((size_t)64 * 256 * 2);
  float* asb  = (float*)alloc((size_t)NN * 4 * 4);
  float* adb  = (float*)alloc((size_t)NN * 4 * 4);
  float* nab  = (float*)alloc((size_t)NN * 4);
  int* rowp = (int*)alloc((size_t)(NN + 1) * 4);
  int* cntb = (int*)alloc((size_t)NN * 4);
  int* curb = (int*)alloc((size_t)NN * 4);
  int* colb = (int*)alloc((size_t)ETOT * 4);
  int* part = (int*)alloc(98 * 4);
  float* gsum = (float*)alloc(4);
  float* psum = (float*)alloc((size_t)BB * 64 * 4);
  float* pmax = (float*)alloc((size_t)BB * 64 * 4);
  float* pcnt = (float*)alloc((size_t)BB * 4);
  float* x3 = (float*)bufB;  // reuse (y2 dead after gemm3)
  (void)ws_size; (void)in_sizes; (void)n_in; (void)out_size;

  hipMemsetAsync(cntb, 0, (size_t)NN * 4, stream);
  hipMemsetAsync(curb, 0, (size_t)NN * 4, stream);
  hipMemsetAsync(gsum, 0, 4, stream);

  // CSR by dst (self-loops appended)
  count_kernel<<<(ETOT + 255) / 256, 256, 0, stream>>>(ei, cntb);
  scan1_kernel<<<98, 512, 0, stream>>>(cntb, rowp, part);
  scan2_kernel<<<1, 1, 0, stream>>>(part, rowp);
  scan3_kernel<<<98, 512, 0, stream>>>(rowp, part);
  fill_kernel<<<(ETOT + 255) / 256, 256, 0, stream>>>(ei, rowp, curb, colb);

  // dtype prep
  convx_kernel<<<(NN * 32 + 255) / 256, 256, 0, stream>>>(x, xb);
  convwT_kernel<<<(256 * 32 + 255) / 256, 256, 0, stream>>>(W1, W1t, 15, 32, 256);
  convwT_kernel<<<(256 * 256 + 255) / 256, 256, 0, stream>>>(W2, W2t, 256, 256, 256);
  convwT_kernel<<<(64 * 256 + 255) / 256, 256, 0, stream>>>(W3, W3t, 256, 256, 64);

  const int GX = (NN + 127) / 128;  // 391
  // layer 1: 15(->32) -> 256
  gemm_bf16_kernel<<<dim3(GX, 4), 256, 0, stream>>>(xb, W1t, bufA, NN, 32, 256);
  score_kernel<4><<<12500, 256, 0, stream>>>(bufA, aS1, aD1, asb, adb);
  agg4_kernel<<<12500, 256, 0, stream>>>(bufA, asb, adb, rowp, colb, b1, bufB);
  // layer 2: 256 -> 256
  gemm_bf16_kernel<<<dim3(GX, 4), 256, 0, stream>>>(bufB, W2t, bufA, NN, 256, 256);
  score_kernel<4><<<12500, 256, 0, stream>>>(bufA, aS2, aD2, asb, adb);
  agg4_kernel<<<12500, 256, 0, stream>>>(bufA, asb, adb, rowp, colb, b2, bufB);
  // layer 3: 256 -> 64
  gemm_bf16_kernel<<<dim3(GX, 1), 256, 0, stream>>>(bufB, W3t, bufA, NN, 256, 64);
  score_kernel<1><<<12500, 256, 0, stream>>>(bufA, aS3, aD3, asb, adb);
  agg1_kernel<<<12500, 256, 0, stream>>>(bufA, asb, adb, rowp, colb, b3, x3);

  // node attention softmax over all N
  na_kernel<<<(NN + 255) / 256, 256, 0, stream>>>(x3, Wna1, bna1, Wna2, bna2, nab);
  na_sum_kernel<<<196, 256, 0, stream>>>(nab, gsum);
  na_write_kernel<<<(NN + 255) / 256, 256, 0, stream>>>(nab, gsum, out + BB);

  // pooling + classifier
  pool_kernel<<<BB, 256, 0, stream>>>(x3, batch, psum, pmax, pcnt);
  cls_kernel<<<BB, 128, 0, stream>>>(psum, pmax, pcnt, Wc1, bc1, Wc2, bc2, Wc3, bc3, out);
}

// Round 4
// 480.017 us; speedup vs baseline: 1.7149x; 1.1228x over previous
//
#include <hip/hip_runtime.h>
#include <math.h>

#define NN 50000
#define EE 800000
#define ETOT (EE + NN)
#define BB 50
#define PC 16  // pooling chunks per graph

typedef unsigned short u16;
typedef __attribute__((ext_vector_type(8))) short short8;
typedef __attribute__((ext_vector_type(4))) float floatx4;

__device__ __forceinline__ float b2f(u16 u) {
  return __int_as_float(((int)u) << 16);
}
__device__ __forceinline__ u16 f2b(float f) {
  unsigned u = __float_as_uint(f);
  unsigned r = (u + 0x7fffu + ((u >> 16) & 1u)) >> 16;
  return (u16)r;
}
__device__ __forceinline__ float readlane_f(float v, int l) {
  return __int_as_float(__builtin_amdgcn_readlane(__float_as_int(v), l));
}

// ---------------- CSR build ----------------
__global__ void count_kernel(const int* __restrict__ ei, int* __restrict__ cnt) {
  int e = blockIdx.x * blockDim.x + threadIdx.x;
  if (e >= ETOT) return;
  int d = (e < EE) ? ei[EE + e] : (e - EE);
  atomicAdd(&cnt[d], 1);
}

__global__ void scan1_kernel(const int* __restrict__ cnt, int* __restrict__ rowp,
                             int* __restrict__ part) {
  __shared__ int s[512];
  int t = threadIdx.x;
  int i = blockIdx.x * 512 + t;
  int v = (i < NN) ? cnt[i] : 0;
  s[t] = v;
  __syncthreads();
  for (int off = 1; off < 512; off <<= 1) {
    int add = (t >= off) ? s[t - off] : 0;
    __syncthreads();
    s[t] += add;
    __syncthreads();
  }
  if (i < NN) rowp[i] = s[t] - v;  // exclusive within block
  if (t == 511) part[blockIdx.x] = s[511];
}

__global__ void scan2_kernel(int* part, int* rowp) {
  int run = 0;
  for (int b = 0; b < 98; ++b) { int v = part[b]; part[b] = run; run += v; }
  rowp[NN] = run;  // == ETOT
}

__global__ void scan3_kernel(int* __restrict__ rowp, const int* __restrict__ part) {
  int i = blockIdx.x * 512 + threadIdx.x;
  if (i < NN) rowp[i] += part[blockIdx.x];
}

__global__ void fill_kernel(const int* __restrict__ ei, const int* __restrict__ rowp,
                            int* __restrict__ cur, int* __restrict__ col) {
  int e = blockIdx.x * blockDim.x + threadIdx.x;
  if (e >= ETOT) return;
  int s, d;
  if (e < EE) { s = ei[e]; d = ei[EE + e]; } else { s = e - EE; d = s; }
  int p = atomicAdd(&cur[d], 1);
  col[rowp[d] + p] = s;
}

// ---------------- dtype prep ----------------
__global__ void convx_kernel(const float* __restrict__ x, u16* __restrict__ xb) {
  int i = blockIdx.x * 256 + threadIdx.x;  // over NN*32 (K padded 15->32)
  if (i >= NN * 32) return;
  int n = i >> 5, c = i & 31;
  xb[i] = (c < 15) ? f2b(x[n * 15 + c]) : (u16)0;
}

// Wt[n][k] = W[k][n] in bf16, K padded with zeros
__global__ void convwT_kernel(const float* __restrict__ W, u16* __restrict__ Wt,
                              int Kreal, int Kp, int Ncols) {
  int i = blockIdx.x * 256 + threadIdx.x;  // over Ncols*Kp
  if (i >= Ncols * Kp) return;
  int n = i / Kp, k = i - n * Kp;
  Wt[i] = (k < Kreal) ? f2b(W[(size_t)k * Ncols + n]) : (u16)0;
}

// ---------------- bf16 MFMA GEMM: C[M,N] = A[M,K] @ Bt[N,K]^T ----------------
// BM=128, BN=64, BK=32. 4 waves as 2x2; each wave 64x32 out (4x2 mfma frags).
__global__ __launch_bounds__(256) void gemm_bf16_kernel(
    const u16* __restrict__ A, const u16* __restrict__ Bt, u16* __restrict__ C,
    int M, int K, int N) {
  __shared__ u16 Al[128][40];
  __shared__ u16 Bl[64][40];
  int R0 = blockIdx.x * 128, C0 = blockIdx.y * 64;
  int wid = threadIdx.x >> 6, lane = threadIdx.x & 63;
  int wr = (wid >> 1) * 64, wc = (wid & 1) * 32;
  int lrow = lane & 15, lk8 = (lane >> 4) * 8;
  floatx4 acc[4][2];
#pragma unroll
  for (int i = 0; i < 4; ++i)
#pragma unroll
    for (int j = 0; j < 2; ++j) acc[i][j] = (floatx4){0.f, 0.f, 0.f, 0.f};

  for (int k0 = 0; k0 < K; k0 += 32) {
#pragma unroll
    for (int c = threadIdx.x; c < 1024; c += 256) {
      int r = c >> 3, off = (c & 7) * 4;
      int gr = R0 + r;
      ushort4 va = make_ushort4(0, 0, 0, 0);
      if (gr < M) va = *(const ushort4*)&A[(size_t)gr * K + k0 + off];
      *(ushort4*)&Al[r][off] = va;
      if (c < 512)
        *(ushort4*)&Bl[r][off] = *(const ushort4*)&Bt[(size_t)(C0 + r) * K + k0 + off];
    }
    __syncthreads();
    short8 a[4], b[2];
#pragma unroll
    for (int i = 0; i < 4; ++i) a[i] = *(const short8*)&Al[wr + i * 16 + lrow][lk8];
#pragma unroll
    for (int j = 0; j < 2; ++j) b[j] = *(const short8*)&Bl[wc + j * 16 + lrow][lk8];
#pragma unroll
    for (int i = 0; i < 4; ++i)
#pragma unroll
      for (int j = 0; j < 2; ++j)
        acc[i][j] = __builtin_amdgcn_mfma_f32_16x16x32_bf16(a[i], b[j], acc[i][j], 0, 0, 0);
    __syncthreads();
  }
  int rq = (lane >> 4) * 4;
#pragma unroll
  for (int i = 0; i < 4; ++i)
#pragma unroll
    for (int j = 0; j < 2; ++j)
#pragma unroll
      for (int q = 0; q < 4; ++q) {
        int gr = R0 + wr + i * 16 + rq + q;
        if (gr < M) C[(size_t)gr * N + C0 + wc + j * 16 + lrow] = f2b(acc[i][j][q]);
      }
}

// ---------------- per-node attention scores (bf16 h) ----------------
template <int H>
__global__ void score_kernel(const u16* __restrict__ h, const float* __restrict__ aS,
                             const float* __restrict__ aD, float* __restrict__ as_o,
                             float* __restrict__ ad_o) {
  const int CT = H * 64;
  int wid = threadIdx.x >> 6, lane = threadIdx.x & 63;
  int n = blockIdx.x * (blockDim.x >> 6) + wid;
  if (n >= NN) return;
  float ps[H], pd[H];
#pragma unroll
  for (int j = 0; j < H; ++j) {
    float hv = b2f(h[(size_t)n * CT + lane + 64 * j]);
    ps[j] = hv * aS[lane + 64 * j];
    pd[j] = hv * aD[lane + 64 * j];
  }
#pragma unroll
  for (int j = 0; j < H; ++j) {
    for (int o = 32; o; o >>= 1) {
      ps[j] += __shfl_xor(ps[j], o, 64);
      pd[j] += __shfl_xor(pd[j], o, 64);
    }
  }
  if (lane == 0) {
#pragma unroll
    for (int j = 0; j < H; ++j) {
      as_o[(size_t)n * H + j] = ps[j];
      ad_o[(size_t)n * H + j] = pd[j];
    }
  }
}

// ---------------- single-pass softmax-aggregate, H=4, bf16 h -> bf16 out ----------------
__global__ __launch_bounds__(256) void agg4_kernel(
    const u16* __restrict__ h, const float* __restrict__ as_i,
    const float* __restrict__ ad_i, const int* __restrict__ rowp,
    const int* __restrict__ col, const float* __restrict__ bias,
    u16* __restrict__ xo) {
  __shared__ float exs[4][64][4];  // [wave][edge-slot][head]
  int wid = threadIdx.x >> 6, lane = threadIdx.x & 63;
  int d = blockIdx.x * 4 + wid;
  int rp0 = rowp[d], deg = rowp[d + 1] - rp0;
  float4 add = *(const float4*)&ad_i[(size_t)d * 4];
  int hj = lane >> 4;  // head of this lane's 4 channels
  float acc0 = 0.f, acc1 = 0.f, acc2 = 0.f, acc3 = 0.f;
  float den0 = 0.f, den1 = 0.f, den2 = 0.f, den3 = 0.f;
  const ushort4* hq = (const ushort4*)h;  // 64 ushort4 per 256-ch row

  for (int base = 0; base < deg; base += 64) {
    int i = base + lane;
    bool valid = i < deg;
    int s = valid ? col[rp0 + i] : 0;
    float4 asv = *(const float4*)&as_i[(size_t)s * 4];
    float e0 = asv.x + add.x, e1 = asv.y + add.y, e2 = asv.z + add.z, e3 = asv.w + add.w;
    e0 = (e0 > 0.f) ? e0 : 0.2f * e0;
    e1 = (e1 > 0.f) ? e1 : 0.2f * e1;
    e2 = (e2 > 0.f) ? e2 : 0.2f * e2;
    e3 = (e3 > 0.f) ? e3 : 0.2f * e3;
    float x0 = valid ? __expf(e0) : 0.f;
    float x1 = valid ? __expf(e1) : 0.f;
    float x2 = valid ? __expf(e2) : 0.f;
    float x3 = valid ? __expf(e3) : 0.f;
    den0 += x0; den1 += x1; den2 += x2; den3 += x3;
    *(float4*)&exs[wid][lane][0] = make_float4(x0, x1, x2, x3);
    __threadfence_block();  // order ds_write before the broadcast ds_reads
    int cnt = min(64, deg - base);
#pragma unroll 2
    for (int k = 0; k < cnt; ++k) {
      int sk = __builtin_amdgcn_readlane(s, k);  // uniform -> SGPR base
      float exk = exs[wid][k][hj];               // broadcast LDS read
      ushort4 hv = hq[(size_t)sk * 64 + lane];
      acc0 += exk * b2f(hv.x);
      acc1 += exk * b2f(hv.y);
      acc2 += exk * b2f(hv.z);
      acc3 += exk * b2f(hv.w);
    }
  }
#pragma unroll
  for (int o = 32; o; o >>= 1) {
    den0 += __shfl_xor(den0, o, 64);
    den1 += __shfl_xor(den1, o, 64);
    den2 += __shfl_xor(den2, o, 64);
    den3 += __shfl_xor(den3, o, 64);
  }
  float den = (hj == 0) ? den0 : (hj == 1) ? den1 : (hj == 2) ? den2 : den3;
  float inv = 1.f / den;
  float4 bv = *(const float4*)&bias[lane * 4];
  float v0 = acc0 * inv + bv.x;
  float v1 = acc1 * inv + bv.y;
  float v2 = acc2 * inv + bv.z;
  float v3 = acc3 * inv + bv.w;
  v0 = (v0 > 0.f) ? v0 : expm1f(v0);
  v1 = (v1 > 0.f) ? v1 : expm1f(v1);
  v2 = (v2 > 0.f) ? v2 : expm1f(v2);
  v3 = (v3 > 0.f) ? v3 : expm1f(v3);
  ushort4 o4;
  o4.x = f2b(v0); o4.y = f2b(v1); o4.z = f2b(v2); o4.w = f2b(v3);
  ((ushort4*)xo)[(size_t)d * 64 + lane] = o4;
}

// ---------------- single-pass softmax-aggregate, H=1, bf16 h -> fp32 out ----------------
__global__ __launch_bounds__(256) void agg1_kernel(
    const u16* __restrict__ h, const float* __restrict__ as_i,
    const float* __restrict__ ad_i, const int* __restrict__ rowp,
    const int* __restrict__ col, const float* __restrict__ bias,
    float* __restrict__ xo) {
  int wid = threadIdx.x >> 6, lane = threadIdx.x & 63;
  int d = blockIdx.x * 4 + wid;
  int rp0 = rowp[d], deg = rowp[d + 1] - rp0;
  float add = ad_i[d];
  float acc = 0.f, den = 0.f;
  for (int base = 0; base < deg; base += 64) {
    int i = base + lane;
    bool valid = i < deg;
    int s = valid ? col[rp0 + i] : 0;
    float e = as_i[s] + add;
    e = (e > 0.f) ? e : 0.2f * e;
    float ex = valid ? __expf(e) : 0.f;
    den += ex;
    int cnt = min(64, deg - base);
#pragma unroll 2
    for (int k = 0; k < cnt; ++k) {
      int sk = __builtin_amdgcn_readlane(s, k);
      float exk = readlane_f(ex, k);
      acc += exk * b2f(h[(size_t)sk * 64 + lane]);
    }
  }
#pragma unroll
  for (int o = 32; o; o >>= 1) den += __shfl_xor(den, o, 64);
  float v = acc / den + bias[lane];
  v = (v > 0.f) ? v : expm1f(v);
  xo[(size_t)d * 64 + lane] = v;
}

// ---------------- node-attention MLP ----------------
__global__ void na_kernel(const float* __restrict__ x3, const float* __restrict__ W1,
                          const float* __restrict__ b1, const float* __restrict__ W2,
                          const float* __restrict__ b2, float* __restrict__ na) {
  __shared__ float Ws[64 * 32];
  __shared__ float W2s[32];
  for (int i = threadIdx.x; i < 2048; i += blockDim.x) Ws[i] = W1[i];
  if (threadIdx.x < 32) W2s[threadIdx.x] = W2[threadIdx.x];
  __syncthreads();
  int n = blockIdx.x * blockDim.x + threadIdx.x;
  if (n >= NN) return;
  float hid[32];
#pragma unroll
  for (int j = 0; j < 32; ++j) hid[j] = b1[j];
  for (int k = 0; k < 64; ++k) {
    float xv = x3[(size_t)n * 64 + k];
#pragma unroll
    for (int j = 0; j < 32; ++j) hid[j] += xv * Ws[k * 32 + j];
  }
  float z = b2[0];
#pragma unroll
  for (int j = 0; j < 32; ++j) z += fmaxf(hid[j], 0.f) * W2s[j];
  na[n] = z;
}

__global__ void na_sum_kernel(const float* __restrict__ na, float* __restrict__ gsum) {
  __shared__ float s[4];
  float acc = 0.f;
  for (int i = blockIdx.x * blockDim.x + threadIdx.x; i < NN; i += gridDim.x * blockDim.x)
    acc += expf(na[i]);
  for (int o = 32; o; o >>= 1) acc += __shfl_xor(acc, o, 64);
  int wid = threadIdx.x >> 6, lane = threadIdx.x & 63;
  if (lane == 0) s[wid] = acc;
  __syncthreads();
  if (threadIdx.x == 0) atomicAdd(gsum, s[0] + s[1] + s[2] + s[3]);
}

__global__ void na_write_kernel(const float* __restrict__ na, const float* __restrict__ gsum,
                                float* __restrict__ out) {
  int n = blockIdx.x * blockDim.x + threadIdx.x;
  if (n >= NN) return;
  out[n] = expf(na[n]) / gsum[0];
}

// ---------------- pooling stage 1: partial sum/max per (graph, chunk) ----------------
__global__ void pool1_kernel(const float* __restrict__ x3, const int* __restrict__ batch,
                             float* __restrict__ ppsum, float* __restrict__ ppmax) {
  int b = blockIdx.x, c = blockIdx.y;
  int lane = threadIdx.x & 63, wid = threadIdx.x >> 6;
  int lo = 0, hi = NN;
  while (lo < hi) { int m = (lo + hi) >> 1; if (batch[m] < b) lo = m + 1; else hi = m; }
  int start = lo;
  lo = start; hi = NN;
  while (lo < hi) { int m = (lo + hi) >> 1; if (batch[m] < b + 1) lo = m + 1; else hi = m; }
  int end = lo;
  int len = end - start;
  int c0 = start + (int)((long)len * c / PC);
  int c1 = start + (int)((long)len * (c + 1) / PC);
  float acc = 0.f, mx = -INFINITY;
  for (int n = c0 + wid; n < c1; n += 4) {
    float v = x3[(size_t)n * 64 + lane];
    acc += v;
    mx = fmaxf(mx, v);
  }
  __shared__ float ssum[4][64], smax[4][64];
  ssum[wid][lane] = acc;
  smax[wid][lane] = mx;
  __syncthreads();
  if (wid == 0) {
    acc = ssum[0][lane] + ssum[1][lane] + ssum[2][lane] + ssum[3][lane];
    mx = fmaxf(fmaxf(smax[0][lane], smax[1][lane]), fmaxf(smax[2][lane], smax[3][lane]));
    size_t o = ((size_t)c * BB + b) * 64 + lane;
    ppsum[o] = acc;
    ppmax[o] = mx;
  }
}

// ---------------- pooling stage 2: fold PC partials ----------------
__global__ void pool2_kernel(const float* __restrict__ ppsum, const float* __restrict__ ppmax,
                             const int* __restrict__ batch, float* __restrict__ psum,
                             float* __restrict__ pmax, float* __restrict__ pcnt) {
  int b = blockIdx.x, lane = threadIdx.x;
  float s = 0.f, m = -INFINITY;
#pragma unroll
  for (int c = 0; c < PC; ++c) {
    size_t o = ((size_t)c * BB + b) * 64 + lane;
    s += ppsum[o];
    m = fmaxf(m, ppmax[o]);
  }
  psum[b * 64 + lane] = s;
  pmax[b * 64 + lane] = m;
  if (lane == 0) {
    int lo = 0, hi = NN;
    while (lo < hi) { int mid = (lo + hi) >> 1; if (batch[mid] < b) lo = mid + 1; else hi = mid; }
    int start = lo;
    lo = start; hi = NN;
    while (lo < hi) { int mid = (lo + hi) >> 1; if (batch[mid] < b + 1) lo = mid + 1; else hi = mid; }
    pcnt[b] = (float)(lo - start);
  }
}

// ---------------- graph classifier ----------------
__global__ void cls_kernel(const float* __restrict__ psum, const float* __restrict__ pmax,
                           const float* __restrict__ pcnt, const float* __restrict__ Wc1,
                           const float* __restrict__ bc1, const float* __restrict__ Wc2,
                           const float* __restrict__ bc2, const float* __restrict__ Wc3,
                           const float* __restrict__ bc3, float* __restrict__ out) {
  __shared__ float g[128], h1[128], h2[64];
  int b = blockIdx.x, t = threadIdx.x;
  float cnt = pcnt[b];
  if (t < 64) {
    g[t] = (cnt > 0.f) ? psum[b * 64 + t] / fmaxf(cnt, 1.f) : 0.f;
    g[64 + t] = (cnt > 0.f) ? pmax[b * 64 + t] : 0.f;
  }
  __syncthreads();
  float v = bc1[t];
  for (int k = 0; k < 128; ++k) v += g[k] * Wc1[k * 128 + t];
  h1[t] = fmaxf(v, 0.f);
  __syncthreads();
  if (t < 64) {
    float v2 = bc2[t];
    for (int k = 0; k < 128; ++k) v2 += h1[k] * Wc2[k * 64 + t];
    h2[t] = fmaxf(v2, 0.f);
  }
  __syncthreads();
  if (t == 0) {
    float z = bc3[0];
    for (int k = 0; k < 64; ++k) z += h2[k] * Wc3[k];
    out[b] = 1.f / (1.f + expf(-z));
  }
}

extern "C" void kernel_launch(void* const* d_in, const int* in_sizes, int n_in,
                              void* d_out, int out_size, void* d_ws, size_t ws_size,
                              hipStream_t stream) {
  const float* x    = (const float*)d_in[0];
  const int*   ei   = (const int*)d_in[1];
  const int*   batch= (const int*)d_in[2];
  const float* W1 = (const float*)d_in[3];
  const float* aS1= (const float*)d_in[4];
  const float* aD1= (const float*)d_in[5];
  const float* b1 = (const float*)d_in[6];
  const float* W2 = (const float*)d_in[7];
  const float* aS2= (const float*)d_in[8];
  const float* aD2= (const float*)d_in[9];
  const float* b2 = (const float*)d_in[10];
  const float* W3 = (const float*)d_in[11];
  const float* aS3= (const float*)d_in[12];
  const float* aD3= (const float*)d_in[13];
  const float* b3 = (const float*)d_in[14];
  const float* Wna1=(const float*)d_in[15];
  const float* bna1=(const float*)d_in[16];
  const float* Wna2=(const float*)d_in[17];
  const float* bna2=(const float*)d_in[18];
  const float* Wc1=(const float*)d_in[19];
  const float* bc1=(const float*)d_in[20];
  const float* Wc2=(const float*)d_in[21];
  const float* bc2=(const float*)d_in[22];
  const float* Wc3=(const float*)d_in[23];
  const float* bc3=(const float*)d_in[24];
  float* out = (float*)d_out;

  // workspace carve-out (~62 MB)
  char* w = (char*)d_ws;
  size_t off = 0;
  auto alloc = [&](size_t bytes) {
    void* p = w + off;
    off = (off + bytes + 255) & ~(size_t)255;
    return p;
  };
  u16* xb   = (u16*)alloc((size_t)NN * 32 * 2);        // padded bf16 input
  u16* bufA = (u16*)alloc((size_t)NN * 256 * 2);       // h1 / h2 / h3
  u16* bufB = (u16*)alloc((size_t)NN * 256 * 2);       // y1 / y2 / x3(fp32)
  u16* W1t  = (u16*)alloc((size_t)256 * 32 * 2);
  u16* W2t  = (u16*)alloc((size_t)256 * 256 * 2);
  u16* W3t  = (u16*)alloc((size_t)64 * 256 * 2);
  float* asb  = (float*)alloc((size_t)NN * 4 * 4);
  float* adb  = (float*)alloc((size_t)NN * 4 * 4);
  float* nab  = (float*)alloc((size_t)NN * 4);
  int* rowp = (int*)alloc((size_t)(NN + 1) * 4);
  int* cntb = (int*)alloc((size_t)NN * 4);
  int* curb = (int*)alloc((size_t)NN * 4);
  int* colb = (int*)alloc((size_t)ETOT * 4);
  int* part = (int*)alloc(98 * 4);
  float* gsum = (float*)alloc(4);
  float* psum = (float*)alloc((size_t)BB * 64 * 4);
  float* pmax = (float*)alloc((size_t)BB * 64 * 4);
  float* pcnt = (float*)alloc((size_t)BB * 4);
  float* ppsum = (float*)alloc((size_t)PC * BB * 64 * 4);
  float* ppmax = (float*)alloc((size_t)PC * BB * 64 * 4);
  float* x3 = (float*)bufB;  // reuse (y2 dead after gemm3)
  (void)ws_size; (void)in_sizes; (void)n_in; (void)out_size;

  hipMemsetAsync(cntb, 0, (size_t)NN * 4, stream);
  hipMemsetAsync(curb, 0, (size_t)NN * 4, stream);
  hipMemsetAsync(gsum, 0, 4, stream);

  // CSR by dst (self-loops appended)
  count_kernel<<<(ETOT + 255) / 256, 256, 0, stream>>>(ei, cntb);
  scan1_kernel<<<98, 512, 0, stream>>>(cntb, rowp, part);
  scan2_kernel<<<1, 1, 0, stream>>>(part, rowp);
  scan3_kernel<<<98, 512, 0, stream>>>(rowp, part);
  fill_kernel<<<(ETOT + 255) / 256, 256, 0, stream>>>(ei, rowp, curb, colb);

  // dtype prep
  convx_kernel<<<(NN * 32 + 255) / 256, 256, 0, stream>>>(x, xb);
  convwT_kernel<<<(256 * 32 + 255) / 256, 256, 0, stream>>>(W1, W1t, 15, 32, 256);
  convwT_kernel<<<(256 * 256 + 255) / 256, 256, 0, stream>>>(W2, W2t, 256, 256, 256);
  convwT_kernel<<<(64 * 256 + 255) / 256, 256, 0, stream>>>(W3, W3t, 256, 256, 64);

  const int GX = (NN + 127) / 128;  // 391
  // layer 1: 15(->32) -> 256
  gemm_bf16_kernel<<<dim3(GX, 4), 256, 0, stream>>>(xb, W1t, bufA, NN, 32, 256);
  score_kernel<4><<<12500, 256, 0, stream>>>(bufA, aS1, aD1, asb, adb);
  agg4_kernel<<<12500, 256, 0, stream>>>(bufA, asb, adb, rowp, colb, b1, bufB);
  // layer 2: 256 -> 256
  gemm_bf16_kernel<<<dim3(GX, 4), 256, 0, stream>>>(bufB, W2t, bufA, NN, 256, 256);
  score_kernel<4><<<12500, 256, 0, stream>>>(bufA, aS2, aD2, asb, adb);
  agg4_kernel<<<12500, 256, 0, stream>>>(bufA, asb, adb, rowp, colb, b2, bufB);
  // layer 3: 256 -> 64
  gemm_bf16_kernel<<<dim3(GX, 1), 256, 0, stream>>>(bufB, W3t, bufA, NN, 256, 64);
  score_kernel<1><<<12500, 256, 0, stream>>>(bufA, aS3, aD3, asb, adb);
  agg1_kernel<<<12500, 256, 0, stream>>>(bufA, asb, adb, rowp, colb, b3, x3);

  // node attention softmax over all N
  na_kernel<<<(NN + 255) / 256, 256, 0, stream>>>(x3, Wna1, bna1, Wna2, bna2, nab);
  na_sum_kernel<<<196, 256, 0, stream>>>(nab, gsum);
  na_write_kernel<<<(NN + 255) / 256, 256, 0, stream>>>(nab, gsum, out + BB);

  // pooling (two-stage) + classifier
  pool1_kernel<<<dim3(BB, PC), 256, 0, stream>>>(x3, batch, ppsum, ppmax);
  pool2_kernel<<<BB, 64, 0, stream>>>(ppsum, ppmax, batch, psum, pmax, pcnt);
  cls_kernel<<<BB, 128, 0, stream>>>(psum, pmax, pcnt, Wc1, bc1, Wc2, bc2, Wc3, bc3, out);
}

// Round 5
// 437.190 us; speedup vs baseline: 1.8829x; 1.0980x over previous
//
#include <hip/hip_runtime.h>
#include <math.h>

#define NN 50000
#define EE 800000
#define ETOT (EE + NN)
#define BB 50
#define PC 16  // pooling chunks per graph

typedef unsigned short u16;
typedef __attribute__((ext_vector_type(8))) short short8;
typedef __attribute__((ext_vector_type(4))) float floatx4;

__device__ __forceinline__ float b2f(u16 u) {
  return __int_as_float(((int)u) << 16);
}
__device__ __forceinline__ u16 f2b(float f) {
  unsigned u = __float_as_uint(f);
  unsigned r = (u + 0x7fffu + ((u >> 16) & 1u)) >> 16;
  return (u16)r;
}
__device__ __forceinline__ float readlane_f(float v, int l) {
  return __int_as_float(__builtin_amdgcn_readlane(__float_as_int(v), l));
}
// bf16 pair -> f32 (2 VALU each)
__device__ __forceinline__ float blo(unsigned w) { return __uint_as_float(w << 16); }
__device__ __forceinline__ float bhi(unsigned w) { return __uint_as_float(w & 0xffff0000u); }

// ---------------- CSR build ----------------
__global__ void count_kernel(const int* __restrict__ ei, int* __restrict__ cnt) {
  int e = blockIdx.x * blockDim.x + threadIdx.x;
  if (e >= ETOT) return;
  int d = (e < EE) ? ei[EE + e] : (e - EE);
  atomicAdd(&cnt[d], 1);
}

__global__ void scan1_kernel(const int* __restrict__ cnt, int* __restrict__ rowp,
                             int* __restrict__ part) {
  __shared__ int s[512];
  int t = threadIdx.x;
  int i = blockIdx.x * 512 + t;
  int v = (i < NN) ? cnt[i] : 0;
  s[t] = v;
  __syncthreads();
  for (int off = 1; off < 512; off <<= 1) {
    int add = (t >= off) ? s[t - off] : 0;
    __syncthreads();
    s[t] += add;
    __syncthreads();
  }
  if (i < NN) rowp[i] = s[t] - v;  // exclusive within block
  if (t == 511) part[blockIdx.x] = s[511];
}

__global__ void scan2_kernel(int* part, int* rowp) {
  int run = 0;
  for (int b = 0; b < 98; ++b) { int v = part[b]; part[b] = run; run += v; }
  rowp[NN] = run;  // == ETOT
}

__global__ void scan3_kernel(int* __restrict__ rowp, const int* __restrict__ part) {
  int i = blockIdx.x * 512 + threadIdx.x;
  if (i < NN) rowp[i] += part[blockIdx.x];
}

__global__ void fill_kernel(const int* __restrict__ ei, const int* __restrict__ rowp,
                            int* __restrict__ cur, int* __restrict__ col) {
  int e = blockIdx.x * blockDim.x + threadIdx.x;
  if (e >= ETOT) return;
  int s, d;
  if (e < EE) { s = ei[e]; d = ei[EE + e]; } else { s = e - EE; d = s; }
  int p = atomicAdd(&cur[d], 1);
  col[rowp[d] + p] = s;
}

// ---------------- fused dtype prep (xb + W1t + W2t + W3t) ----------------
__global__ void prep_kernel(const float* __restrict__ x, const float* __restrict__ W1,
                            const float* __restrict__ W2, const float* __restrict__ W3,
                            u16* __restrict__ xb, u16* __restrict__ W1t,
                            u16* __restrict__ W2t, u16* __restrict__ W3t) {
  const int T0 = NN * 32, T1 = T0 + 8192, T2 = T1 + 65536, T3 = T2 + 16384;
  int i = blockIdx.x * 256 + threadIdx.x;
  if (i < T0) {
    int n = i >> 5, c = i & 31;
    xb[i] = (c < 15) ? f2b(x[n * 15 + c]) : (u16)0;
  } else if (i < T1) {
    int j = i - T0, n = j >> 5, k = j & 31;
    W1t[j] = (k < 15) ? f2b(W1[k * 256 + n]) : (u16)0;
  } else if (i < T2) {
    int j = i - T1, n = j >> 8, k = j & 255;
    W2t[j] = f2b(W2[k * 256 + n]);
  } else if (i < T3) {
    int j = i - T2, n = j >> 8, k = j & 255;
    W3t[j] = f2b(W3[k * 64 + n]);
  }
}

// ---------------- bf16 MFMA GEMM: C[M,N] = A[M,K] @ Bt[N,K]^T ----------------
__global__ __launch_bounds__(256) void gemm_bf16_kernel(
    const u16* __restrict__ A, const u16* __restrict__ Bt, u16* __restrict__ C,
    int M, int K, int N) {
  __shared__ u16 Al[128][40];
  __shared__ u16 Bl[64][40];
  int R0 = blockIdx.x * 128, C0 = blockIdx.y * 64;
  int wid = threadIdx.x >> 6, lane = threadIdx.x & 63;
  int wr = (wid >> 1) * 64, wc = (wid & 1) * 32;
  int lrow = lane & 15, lk8 = (lane >> 4) * 8;
  floatx4 acc[4][2];
#pragma unroll
  for (int i = 0; i < 4; ++i)
#pragma unroll
    for (int j = 0; j < 2; ++j) acc[i][j] = (floatx4){0.f, 0.f, 0.f, 0.f};

  for (int k0 = 0; k0 < K; k0 += 32) {
#pragma unroll
    for (int c = threadIdx.x; c < 1024; c += 256) {
      int r = c >> 3, off = (c & 7) * 4;
      int gr = R0 + r;
      ushort4 va = make_ushort4(0, 0, 0, 0);
      if (gr < M) va = *(const ushort4*)&A[(size_t)gr * K + k0 + off];
      *(ushort4*)&Al[r][off] = va;
      if (c < 512)
        *(ushort4*)&Bl[r][off] = *(const ushort4*)&Bt[(size_t)(C0 + r) * K + k0 + off];
    }
    __syncthreads();
    short8 a[4], b[2];
#pragma unroll
    for (int i = 0; i < 4; ++i) a[i] = *(const short8*)&Al[wr + i * 16 + lrow][lk8];
#pragma unroll
    for (int j = 0; j < 2; ++j) b[j] = *(const short8*)&Bl[wc + j * 16 + lrow][lk8];
#pragma unroll
    for (int i = 0; i < 4; ++i)
#pragma unroll
      for (int j = 0; j < 2; ++j)
        acc[i][j] = __builtin_amdgcn_mfma_f32_16x16x32_bf16(a[i], b[j], acc[i][j], 0, 0, 0);
    __syncthreads();
  }
  int rq = (lane >> 4) * 4;
#pragma unroll
  for (int i = 0; i < 4; ++i)
#pragma unroll
    for (int j = 0; j < 2; ++j)
#pragma unroll
      for (int q = 0; q < 4; ++q) {
        int gr = R0 + wr + i * 16 + rq + q;
        if (gr < M) C[(size_t)gr * N + C0 + wc + j * 16 + lrow] = f2b(acc[i][j][q]);
      }
}

// ---------------- per-node attention scores (bf16 h) ----------------
template <int H>
__global__ void score_kernel(const u16* __restrict__ h, const float* __restrict__ aS,
                             const float* __restrict__ aD, float* __restrict__ as_o,
                             float* __restrict__ ad_o) {
  const int CT = H * 64;
  int wid = threadIdx.x >> 6, lane = threadIdx.x & 63;
  int n = blockIdx.x * (blockDim.x >> 6) + wid;
  if (n >= NN) return;
  float ps[H], pd[H];
#pragma unroll
  for (int j = 0; j < H; ++j) {
    float hv = b2f(h[(size_t)n * CT + lane + 64 * j]);
    ps[j] = hv * aS[lane + 64 * j];
    pd[j] = hv * aD[lane + 64 * j];
  }
#pragma unroll
  for (int j = 0; j < H; ++j) {
    for (int o = 32; o; o >>= 1) {
      ps[j] += __shfl_xor(ps[j], o, 64);
      pd[j] += __shfl_xor(pd[j], o, 64);
    }
  }
  if (lane == 0) {
#pragma unroll
    for (int j = 0; j < H; ++j) {
      as_o[(size_t)n * H + j] = ps[j];
      ad_o[(size_t)n * H + j] = pd[j];
    }
  }
}

// ---------------- single-pass softmax-aggregate, H=4, bf16 h -> bf16 out ----------------
// Inner gather unrolled x4 (exact tail) so each wave keeps 4 independent
// 512B-row gathers in flight; bf16->f32 via shl/and bit tricks.
__global__ __launch_bounds__(256) void agg4_kernel(
    const u16* __restrict__ h, const float* __restrict__ as_i,
    const float* __restrict__ ad_i, const int* __restrict__ rowp,
    const int* __restrict__ col, const float* __restrict__ bias,
    u16* __restrict__ xo) {
  __shared__ float exs[4][64][4];  // [wave][edge-slot][head]
  int wid = threadIdx.x >> 6, lane = threadIdx.x & 63;
  int d = blockIdx.x * 4 + wid;
  int rp0 = rowp[d], deg = rowp[d + 1] - rp0;
  float4 add = *(const float4*)&ad_i[(size_t)d * 4];
  int hj = lane >> 4;  // head of this lane's 4 channels
  int lq = lane << 2;  // first channel owned by this lane
  float acc0 = 0.f, acc1 = 0.f, acc2 = 0.f, acc3 = 0.f;
  float den0 = 0.f, den1 = 0.f, den2 = 0.f, den3 = 0.f;

  for (int base = 0; base < deg; base += 64) {
    int i = base + lane;
    bool valid = i < deg;
    int s = valid ? col[rp0 + i] : 0;
    float4 asv = *(const float4*)&as_i[(size_t)s * 4];
    float e0 = asv.x + add.x, e1 = asv.y + add.y, e2 = asv.z + add.z, e3 = asv.w + add.w;
    e0 = (e0 > 0.f) ? e0 : 0.2f * e0;
    e1 = (e1 > 0.f) ? e1 : 0.2f * e1;
    e2 = (e2 > 0.f) ? e2 : 0.2f * e2;
    e3 = (e3 > 0.f) ? e3 : 0.2f * e3;
    float x0 = valid ? __expf(e0) : 0.f;
    float x1 = valid ? __expf(e1) : 0.f;
    float x2 = valid ? __expf(e2) : 0.f;
    float x3 = valid ? __expf(e3) : 0.f;
    den0 += x0; den1 += x1; den2 += x2; den3 += x3;
    *(float4*)&exs[wid][lane][0] = make_float4(x0, x1, x2, x3);
    __threadfence_block();  // order ds_write before the broadcast ds_reads
    int cnt = min(64, deg - base);
    int k4 = cnt & ~3;
    for (int k = 0; k < k4; k += 4) {
      int s0 = __builtin_amdgcn_readlane(s, k);
      int s1 = __builtin_amdgcn_readlane(s, k + 1);
      int s2 = __builtin_amdgcn_readlane(s, k + 2);
      int s3 = __builtin_amdgcn_readlane(s, k + 3);
      float q0 = exs[wid][k][hj];
      float q1 = exs[wid][k + 1][hj];
      float q2 = exs[wid][k + 2][hj];
      float q3 = exs[wid][k + 3][hj];
      uint2 w0 = *(const uint2*)&h[(size_t)s0 * 256 + lq];
      uint2 w1 = *(const uint2*)&h[(size_t)s1 * 256 + lq];
      uint2 w2 = *(const uint2*)&h[(size_t)s2 * 256 + lq];
      uint2 w3 = *(const uint2*)&h[(size_t)s3 * 256 + lq];
      acc0 += q0 * blo(w0.x); acc1 += q0 * bhi(w0.x);
      acc2 += q0 * blo(w0.y); acc3 += q0 * bhi(w0.y);
      acc0 += q1 * blo(w1.x); acc1 += q1 * bhi(w1.x);
      acc2 += q1 * blo(w1.y); acc3 += q1 * bhi(w1.y);
      acc0 += q2 * blo(w2.x); acc1 += q2 * bhi(w2.x);
      acc2 += q2 * blo(w2.y); acc3 += q2 * bhi(w2.y);
      acc0 += q3 * blo(w3.x); acc1 += q3 * bhi(w3.x);
      acc2 += q3 * blo(w3.y); acc3 += q3 * bhi(w3.y);
    }
    for (int k = k4; k < cnt; ++k) {
      int sk = __builtin_amdgcn_readlane(s, k);
      float qk = exs[wid][k][hj];
      uint2 wk = *(const uint2*)&h[(size_t)sk * 256 + lq];
      acc0 += qk * blo(wk.x); acc1 += qk * bhi(wk.x);
      acc2 += qk * blo(wk.y); acc3 += qk * bhi(wk.y);
    }
  }
#pragma unroll
  for (int o = 32; o; o >>= 1) {
    den0 += __shfl_xor(den0, o, 64);
    den1 += __shfl_xor(den1, o, 64);
    den2 += __shfl_xor(den2, o, 64);
    den3 += __shfl_xor(den3, o, 64);
  }
  float den = (hj == 0) ? den0 : (hj == 1) ? den1 : (hj == 2) ? den2 : den3;
  float inv = 1.f / den;
  float4 bv = *(const float4*)&bias[lq];
  float v0 = acc0 * inv + bv.x;
  float v1 = acc1 * inv + bv.y;
  float v2 = acc2 * inv + bv.z;
  float v3 = acc3 * inv + bv.w;
  v0 = (v0 > 0.f) ? v0 : expm1f(v0);
  v1 = (v1 > 0.f) ? v1 : expm1f(v1);
  v2 = (v2 > 0.f) ? v2 : expm1f(v2);
  v3 = (v3 > 0.f) ? v3 : expm1f(v3);
  ushort4 o4;
  o4.x = f2b(v0); o4.y = f2b(v1); o4.z = f2b(v2); o4.w = f2b(v3);
  ((ushort4*)xo)[(size_t)d * 64 + lane] = o4;
}

// ---------------- single-pass softmax-aggregate, H=1, bf16 h -> fp32 out ----------------
__global__ __launch_bounds__(256) void agg1_kernel(
    const u16* __restrict__ h, const float* __restrict__ as_i,
    const float* __restrict__ ad_i, const int* __restrict__ rowp,
    const int* __restrict__ col, const float* __restrict__ bias,
    float* __restrict__ xo) {
  int wid = threadIdx.x >> 6, lane = threadIdx.x & 63;
  int d = blockIdx.x * 4 + wid;
  int rp0 = rowp[d], deg = rowp[d + 1] - rp0;
  float add = ad_i[d];
  float acc = 0.f, den = 0.f;
  for (int base = 0; base < deg; base += 64) {
    int i = base + lane;
    bool valid = i < deg;
    int s = valid ? col[rp0 + i] : 0;
    float e = as_i[s] + add;
    e = (e > 0.f) ? e : 0.2f * e;
    float ex = valid ? __expf(e) : 0.f;
    den += ex;
    int cnt = min(64, deg - base);
    int k4 = cnt & ~3;
    for (int k = 0; k < k4; k += 4) {
      int s0 = __builtin_amdgcn_readlane(s, k);
      int s1 = __builtin_amdgcn_readlane(s, k + 1);
      int s2 = __builtin_amdgcn_readlane(s, k + 2);
      int s3 = __builtin_amdgcn_readlane(s, k + 3);
      float q0 = readlane_f(ex, k);
      float q1 = readlane_f(ex, k + 1);
      float q2 = readlane_f(ex, k + 2);
      float q3 = readlane_f(ex, k + 3);
      float h0 = b2f(h[(size_t)s0 * 64 + lane]);
      float h1 = b2f(h[(size_t)s1 * 64 + lane]);
      float h2 = b2f(h[(size_t)s2 * 64 + lane]);
      float h3 = b2f(h[(size_t)s3 * 64 + lane]);
      acc += q0 * h0 + q1 * h1 + q2 * h2 + q3 * h3;
    }
    for (int k = k4; k < cnt; ++k) {
      int sk = __builtin_amdgcn_readlane(s, k);
      float qk = readlane_f(ex, k);
      acc += qk * b2f(h[(size_t)sk * 64 + lane]);
    }
  }
#pragma unroll
  for (int o = 32; o; o >>= 1) den += __shfl_xor(den, o, 64);
  float v = acc / den + bias[lane];
  v = (v > 0.f) ? v : expm1f(v);
  xo[(size_t)d * 64 + lane] = v;
}

// ---------------- node-attention MLP + fused exp/sum ----------------
__global__ void na_kernel(const float* __restrict__ x3, const float* __restrict__ W1,
                          const float* __restrict__ b1, const float* __restrict__ W2,
                          const float* __restrict__ b2, float* __restrict__ na,
                          float* __restrict__ gsum) {
  __shared__ float Ws[64 * 32];
  __shared__ float W2s[32];
  __shared__ float sred[4];
  for (int i = threadIdx.x; i < 2048; i += blockDim.x) Ws[i] = W1[i];
  if (threadIdx.x < 32) W2s[threadIdx.x] = W2[threadIdx.x];
  __syncthreads();
  int n = blockIdx.x * blockDim.x + threadIdx.x;
  float ez = 0.f;
  if (n < NN) {
    float hid[32];
#pragma unroll
    for (int j = 0; j < 32; ++j) hid[j] = b1[j];
    for (int k = 0; k < 64; ++k) {
      float xv = x3[(size_t)n * 64 + k];
#pragma unroll
      for (int j = 0; j < 32; ++j) hid[j] += xv * Ws[k * 32 + j];
    }
    float z = b2[0];
#pragma unroll
    for (int j = 0; j < 32; ++j) z += fmaxf(hid[j], 0.f) * W2s[j];
    ez = __expf(z);
    na[n] = ez;
  }
  // block-sum of ez -> one atomic
  float acc = ez;
  for (int o = 32; o; o >>= 1) acc += __shfl_xor(acc, o, 64);
  int wid = threadIdx.x >> 6, lane = threadIdx.x & 63;
  if (lane == 0) sred[wid] = acc;
  __syncthreads();
  if (threadIdx.x == 0) atomicAdd(gsum, sred[0] + sred[1] + sred[2] + sred[3]);
}

__global__ void na_write_kernel(const float* __restrict__ na, const float* __restrict__ gsum,
                                float* __restrict__ out) {
  int n = blockIdx.x * blockDim.x + threadIdx.x;
  if (n >= NN) return;
  out[n] = na[n] / gsum[0];
}

// ---------------- pooling stage 1: partial sum/max per (graph, chunk) ----------------
__global__ void pool1_kernel(const float* __restrict__ x3, const int* __restrict__ batch,
                             float* __restrict__ ppsum, float* __restrict__ ppmax) {
  int b = blockIdx.x, c = blockIdx.y;
  int lane = threadIdx.x & 63, wid = threadIdx.x >> 6;
  int lo = 0, hi = NN;
  while (lo < hi) { int m = (lo + hi) >> 1; if (batch[m] < b) lo = m + 1; else hi = m; }
  int start = lo;
  lo = start; hi = NN;
  while (lo < hi) { int m = (lo + hi) >> 1; if (batch[m] < b + 1) lo = m + 1; else hi = m; }
  int end = lo;
  int len = end - start;
  int c0 = start + (int)((long)len * c / PC);
  int c1 = start + (int)((long)len * (c + 1) / PC);
  float acc = 0.f, mx = -INFINITY;
  for (int n = c0 + wid; n < c1; n += 4) {
    float v = x3[(size_t)n * 64 + lane];
    acc += v;
    mx = fmaxf(mx, v);
  }
  __shared__ float ssum[4][64], smax[4][64];
  ssum[wid][lane] = acc;
  smax[wid][lane] = mx;
  __syncthreads();
  if (wid == 0) {
    acc = ssum[0][lane] + ssum[1][lane] + ssum[2][lane] + ssum[3][lane];
    mx = fmaxf(fmaxf(smax[0][lane], smax[1][lane]), fmaxf(smax[2][lane], smax[3][lane]));
    size_t o = ((size_t)c * BB + b) * 64 + lane;
    ppsum[o] = acc;
    ppmax[o] = mx;
  }
}

// ---------------- pooling stage 2: fold PC partials ----------------
__global__ void pool2_kernel(const float* __restrict__ ppsum, const float* __restrict__ ppmax,
                             const int* __restrict__ batch, float* __restrict__ psum,
                             float* __restrict__ pmax, float* __restrict__ pcnt) {
  int b = blockIdx.x, lane = threadIdx.x;
  float s = 0.f, m = -INFINITY;
#pragma unroll
  for (int c = 0; c < PC; ++c) {
    size_t o = ((size_t)c * BB + b) * 64 + lane;
    s += ppsum[o];
    m = fmaxf(m, ppmax[o]);
  }
  psum[b * 64 + lane] = s;
  pmax[b * 64 + lane] = m;
  if (lane == 0) {
    int lo = 0, hi = NN;
    while (lo < hi) { int mid = (lo + hi) >> 1; if (batch[mid] < b) lo = mid + 1; else hi = mid; }
    int start = lo;
    lo = start; hi = NN;
    while (lo < hi) { int mid = (lo + hi) >> 1; if (batch[mid] < b + 1) lo = mid + 1; else hi = mid; }
    pcnt[b] = (float)(lo - start);
  }
}

// ---------------- graph classifier ----------------
__global__ void cls_kernel(const float* __restrict__ psum, const float* __restrict__ pmax,
                           const float* __restrict__ pcnt, const float* __restrict__ Wc1,
                           const float* __restrict__ bc1, const float* __restrict__ Wc2,
                           const float* __restrict__ bc2, const float* __restrict__ Wc3,
                           const float* __restrict__ bc3, float* __restrict__ out) {
  __shared__ float g[128], h1[128], h2[64];
  int b = blockIdx.x, t = threadIdx.x;
  float cnt = pcnt[b];
  if (t < 64) {
    g[t] = (cnt > 0.f) ? psum[b * 64 + t] / fmaxf(cnt, 1.f) : 0.f;
    g[64 + t] = (cnt > 0.f) ? pmax[b * 64 + t] : 0.f;
  }
  __syncthreads();
  float v = bc1[t];
  for (int k = 0; k < 128; ++k) v += g[k] * Wc1[k * 128 + t];
  h1[t] = fmaxf(v, 0.f);
  __syncthreads();
  if (t < 64) {
    float v2 = bc2[t];
    for (int k = 0; k < 128; ++k) v2 += h1[k] * Wc2[k * 64 + t];
    h2[t] = fmaxf(v2, 0.f);
  }
  __syncthreads();
  if (t == 0) {
    float z = bc3[0];
    for (int k = 0; k < 64; ++k) z += h2[k] * Wc3[k];
    out[b] = 1.f / (1.f + expf(-z));
  }
}

extern "C" void kernel_launch(void* const* d_in, const int* in_sizes, int n_in,
                              void* d_out, int out_size, void* d_ws, size_t ws_size,
                              hipStream_t stream) {
  const float* x    = (const float*)d_in[0];
  const int*   ei   = (const int*)d_in[1];
  const int*   batch= (const int*)d_in[2];
  const float* W1 = (const float*)d_in[3];
  const float* aS1= (const float*)d_in[4];
  const float* aD1= (const float*)d_in[5];
  const float* b1 = (const float*)d_in[6];
  const float* W2 = (const float*)d_in[7];
  const float* aS2= (const float*)d_in[8];
  const float* aD2= (const float*)d_in[9];
  const float* b2 = (const float*)d_in[10];
  const float* W3 = (const float*)d_in[11];
  const float* aS3= (const float*)d_in[12];
  const float* aD3= (const float*)d_in[13];
  const float* b3 = (const float*)d_in[14];
  const float* Wna1=(const float*)d_in[15];
  const float* bna1=(const float*)d_in[16];
  const float* Wna2=(const float*)d_in[17];
  const float* bna2=(const float*)d_in[18];
  const float* Wc1=(const float*)d_in[19];
  const float* bc1=(const float*)d_in[20];
  const float* Wc2=(const float*)d_in[21];
  const float* bc2=(const float*)d_in[22];
  const float* Wc3=(const float*)d_in[23];
  const float* bc3=(const float*)d_in[24];
  float* out = (float*)d_out;

  // workspace carve-out (~62 MB)
  char* w = (char*)d_ws;
  size_t off = 0;
  auto alloc = [&](size_t bytes) {
    void* p = w + off;
    off = (off + bytes + 255) & ~(size_t)255;
    return p;
  };
  u16* xb   = (u16*)alloc((size_t)NN * 32 * 2);        // padded bf16 input
  u16* bufA = (u16*)alloc((size_t)NN * 256 * 2);       // h1 / h2 / h3
  u16* bufB = (u16*)alloc((size_t)NN * 256 * 2);       // y1 / y2 / x3(fp32)
  u16* W1t  = (u16*)alloc((size_t)256 * 32 * 2);
  u16* W2t  = (u16*)alloc((size_t)256 * 256 * 2);
  u16* W3t  = (u16*)alloc((size_t)64 * 256 * 2);
  float* asb  = (float*)alloc((size_t)NN * 4 * 4);
  float* adb  = (float*)alloc((size_t)NN * 4 * 4);
  float* nab  = (float*)alloc((size_t)NN * 4);
  int* rowp = (int*)alloc((size_t)(NN + 1) * 4);
  // cntb, curb, gsum contiguous -> single memset
  int* cntb = (int*)alloc((size_t)NN * 4);
  int* curb = (int*)alloc((size_t)NN * 4);
  float* gsum = (float*)alloc(256);
  size_t zspan = (size_t)((char*)gsum + 256 - (char*)cntb);
  int* colb = (int*)alloc((size_t)ETOT * 4);
  int* part = (int*)alloc(98 * 4);
  float* psum = (float*)alloc((size_t)BB * 64 * 4);
  float* pmax = (float*)alloc((size_t)BB * 64 * 4);
  float* pcnt = (float*)alloc((size_t)BB * 4);
  float* ppsum = (float*)alloc((size_t)PC * BB * 64 * 4);
  float* ppmax = (float*)alloc((size_t)PC * BB * 64 * 4);
  float* x3 = (float*)bufB;  // reuse (y2 dead after gemm3)
  (void)ws_size; (void)in_sizes; (void)n_in; (void)out_size;

  hipMemsetAsync(cntb, 0, zspan, stream);

  // CSR by dst (self-loops appended)
  count_kernel<<<(ETOT + 255) / 256, 256, 0, stream>>>(ei, cntb);
  scan1_kernel<<<98, 512, 0, stream>>>(cntb, rowp, part);
  scan2_kernel<<<1, 1, 0, stream>>>(part, rowp);
  scan3_kernel<<<98, 512, 0, stream>>>(rowp, part);
  fill_kernel<<<(ETOT + 255) / 256, 256, 0, stream>>>(ei, rowp, curb, colb);

  // fused dtype prep
  const int PREP_TOT = NN * 32 + 8192 + 65536 + 16384;
  prep_kernel<<<(PREP_TOT + 255) / 256, 256, 0, stream>>>(x, W1, W2, W3, xb, W1t, W2t, W3t);

  const int GX = (NN + 127) / 128;  // 391
  // layer 1: 15(->32) -> 256
  gemm_bf16_kernel<<<dim3(GX, 4), 256, 0, stream>>>(xb, W1t, bufA, NN, 32, 256);
  score_kernel<4><<<12500, 256, 0, stream>>>(bufA, aS1, aD1, asb, adb);
  agg4_kernel<<<12500, 256, 0, stream>>>(bufA, asb, adb, rowp, colb, b1, bufB);
  // layer 2: 256 -> 256
  gemm_bf16_kernel<<<dim3(GX, 4), 256, 0, stream>>>(bufB, W2t, bufA, NN, 256, 256);
  score_kernel<4><<<12500, 256, 0, stream>>>(bufA, aS2, aD2, asb, adb);
  agg4_kernel<<<12500, 256, 0, stream>>>(bufA, asb, adb, rowp, colb, b2, bufB);
  // layer 3: 256 -> 64
  gemm_bf16_kernel<<<dim3(GX, 1), 256, 0, stream>>>(bufB, W3t, bufA, NN, 256, 64);
  score_kernel<1><<<12500, 256, 0, stream>>>(bufA, aS3, aD3, asb, adb);
  agg1_kernel<<<12500, 256, 0, stream>>>(bufA, asb, adb, rowp, colb, b3, x3);

  // node attention softmax over all N (MLP + exp + sum fused)
  na_kernel<<<(NN + 255) / 256, 256, 0, stream>>>(x3, Wna1, bna1, Wna2, bna2, nab, gsum);
  na_write_kernel<<<(NN + 255) / 256, 256, 0, stream>>>(nab, gsum, out + BB);

  // pooling (two-stage) + classifier
  pool1_kernel<<<dim3(BB, PC), 256, 0, stream>>>(x3, batch, ppsum, ppmax);
  pool2_kernel<<<BB, 64, 0, stream>>>(ppsum, ppmax, batch, psum, pmax, pcnt);
  cls_kernel<<<BB, 128, 0, stream>>>(psum, pmax, pcnt, Wc1, bc1, Wc2, bc2, Wc3, bc3, out);
}